// Round 6
// baseline (941.949 us; speedup 1.0000x reference)
//
#include <hip/hip_runtime.h>

typedef unsigned short u16;
typedef __attribute__((ext_vector_type(8))) short short8;
typedef __attribute__((ext_vector_type(8))) unsigned short u16x8;
typedef __attribute__((ext_vector_type(4))) unsigned short u16x4;
typedef __attribute__((ext_vector_type(4))) float f32x4;

#define DEVINL __device__ __forceinline__

DEVINL float bf2f(u16 v) { return __builtin_bit_cast(float, (unsigned int)v << 16); }
DEVINL u16 f2bf(float f) {
  unsigned int u = __builtin_bit_cast(unsigned int, f);
  u += 0x7fffu + ((u >> 16) & 1u);
  return (u16)(u >> 16);
}

// polymorphic scalar input load: flag=1 -> bf16, flag=0 -> f32
DEVINL float loadx(const void* p, size_t i, int flag) {
  return flag ? bf2f(((const u16*)p)[i]) : ((const float*)p)[i];
}

DEVINL f32x4 mfma16(short8 a, short8 b, f32x4 c) {
  return __builtin_amdgcn_mfma_f32_16x16x32_bf16(a, b, c, 0, 0, 0);
}

// async global->LDS, 16B per lane. LDS dest must be wave-uniform base + lane*16.
DEVINL void gload16(const u16* g, u16* l) {
  __builtin_amdgcn_global_load_lds(
      (const __attribute__((address_space(1))) unsigned int*)g,
      (__attribute__((address_space(3))) unsigned int*)l,
      16, 0, 0);
}

#define WAIT_VM(n) asm volatile("s_waitcnt vmcnt(" #n ")" ::: "memory")
#define SBAR() __builtin_amdgcn_s_barrier()
#define SCHED_FENCE() __builtin_amdgcn_sched_barrier(0)

// ---------------------------------------------------------------------------
// dtype detector (unchanged)
__global__ void k_detect(const unsigned int* __restrict__ xw, int* __restrict__ flag)
{
  const int t = threadIdx.x;
  int cnt = 0;
  for (int i = t; i < 4096; i += 256) {
    unsigned int w = xw[i];
    unsigned int h = w & 0xFFFFu;
    unsigned int e = (h >> 7) & 0xFFu;
    if (((h & 0x7FFFu) == 0u) || (e >= 117u && e <= 130u)) cnt++;
  }
  #pragma unroll
  for (int d = 1; d < 64; d <<= 1) cnt += __shfl_xor(cnt, d);
  __shared__ int acc[4];
  if ((t & 63) == 0) acc[t >> 6] = cnt;
  __syncthreads();
  if (t == 0) *flag = ((acc[0] + acc[1] + acc[2] + acc[3]) > 2048) ? 1 : 0;
}

// ---------------------------------------------------------------------------
// prep: W' = W * g (bf16), wsum[o] = sum_c W'[o,c], cb[o] = bias[o] + sum W*beta
__global__ void k_prep_fold(const void* __restrict__ w, const void* __restrict__ g,
                            const void* __restrict__ beta, const void* __restrict__ wbias,
                            const int* __restrict__ dflag,
                            u16* __restrict__ wp, float* __restrict__ wsum, float* __restrict__ cb,
                            int rows, int K, int KP)
{
  const int flag = *dflag;
  const int o = blockIdx.x;
  const int lane = threadIdx.x; // 64
  float ws = 0.f, c = 0.f;
  if (o < rows) {
    for (int k = lane; k < KP; k += 64) {
      u16 outv = 0;
      if (k < K) {
        float wv = loadx(w, (size_t)o * K + k, flag);
        float gv = loadx(g, k, flag);
        outv = f2bf(wv * gv);
        ws += bf2f(outv);
        c  += wv * loadx(beta, k, flag);
      }
      wp[(size_t)o * KP + k] = outv;
    }
  } else {
    for (int k = lane; k < KP; k += 64) wp[(size_t)o * KP + k] = 0;
  }
  #pragma unroll
  for (int d = 1; d < 64; d <<= 1) { ws += __shfl_xor(ws, d); c += __shfl_xor(c, d); }
  if (lane == 0) { wsum[o] = ws; cb[o] = (o < rows) ? (c + loadx(wbias, o, flag)) : 0.f; }
}

// zero-padded bf16 copy of a weight matrix (input f32 or bf16 per flag)
__global__ void k_prep_pad(const void* __restrict__ w, const int* __restrict__ dflag,
                           u16* __restrict__ wp, int rows, int K, int KP, long total)
{
  const int flag = *dflag;
  long i = (long)blockIdx.x * 256 + threadIdx.x;
  if (i >= total) return;
  int r = (int)(i / KP), c2 = (int)(i % KP);
  wp[i] = (r < rows && c2 < K) ? f2bf(loadx(w, (size_t)r * K + c2, flag)) : (u16)0;
}

// ---------------------------------------------------------------------------
// repack row-major padded [RP][KP] -> fragment-major:
// dst[(f*nK + ks)*512 + l*8 + j] = src[(f*16 + (l&15))*KP + ks*32 + (l>>4)*8 + j]
// so a ds_read_b128 of one MFMA fragment is lane-linear (conflict-free), and
// global_load_lds staging (lane-linear dest) needs no per-lane LDS scatter.
__global__ void k_repack(const u16* __restrict__ src, u16* __restrict__ dst, int RP, int KP)
{
  const int nK = KP / 32;
  long i = (long)blockIdx.x * 256 + threadIdx.x;   // one u16x8 each
  if (i * 8 >= (long)RP * KP) return;
  int l = (int)(i & 63);
  long fk = i >> 6;
  int ks = (int)(fk % nK), f = (int)(fk / nK);
  const u16* s = src + (size_t)(f * 16 + (l & 15)) * KP + ks * 32 + ((l >> 4) & 3) * 8;
  *(u16x8*)(dst + i * 8) = *(const u16x8*)s;
}

// ---------------------------------------------------------------------------
// transpose chunk of x [16][392][4096] -> xt [S*4096][416] bf16 (pad cols zeroed)
__global__ __launch_bounds__(256) void k_transpose(const void* __restrict__ xraw,
                                                   const int* __restrict__ dflag,
                                                   u16* __restrict__ xt, int jg0)
{
  __shared__ u16 ts[64][72];
  const int flag = *dflag;
  const int t = threadIdx.x;
  const int j0l = blockIdx.x * 64;
  const int j0g = jg0 + j0l;
  const int c0 = blockIdx.y * 64;
  const int c_l = t >> 2;
  const int c = c0 + c_l;
  const int bb = j0g >> 12;
  const int hw0 = j0g & 4095;

  #pragma unroll
  for (int u = 0; u < 2; ++u) {
    int jp = u * 32 + (t & 3) * 8;
    u16 vv[8] = {0, 0, 0, 0, 0, 0, 0, 0};
    if (c < 392) {
      size_t base = (((size_t)(bb * 392 + c)) << 12) + hw0 + jp;
      if (flag) {
        u16x8 v = *(const u16x8*)((const u16*)xraw + base);
        #pragma unroll
        for (int i = 0; i < 8; ++i) vv[i] = v[i];
      } else {
        const float* xf = (const float*)xraw + base;
        f32x4 a = *(const f32x4*)xf;
        f32x4 b = *(const f32x4*)(xf + 4);
        #pragma unroll
        for (int i = 0; i < 4; ++i) { vv[i] = f2bf(a[i]); vv[4 + i] = f2bf(b[i]); }
      }
    }
    #pragma unroll
    for (int i = 0; i < 8; ++i) ts[jp + i][c_l] = vv[i];
  }
  __syncthreads();
  const int j_l = t >> 2;
  #pragma unroll
  for (int u = 0; u < 2; ++u) {
    int cp = u * 32 + (t & 3) * 8;
    u16x8 w;
    #pragma unroll
    for (int i = 0; i < 8; ++i) w[i] = ts[j_l][cp + i];
    int cg = c0 + cp;
    if (cg < 416) *(u16x8*)(xt + (size_t)(j0l + j_l) * 416 + cg) = w;
  }
}

// ---------------------------------------------------------------------------
// transpose chunk-local attention output att [s][392][4096] -> aout [.][416]
__global__ __launch_bounds__(256) void k_att_tr(const u16* __restrict__ att,
                                                u16* __restrict__ aout)
{
  __shared__ u16 ts[64][72];
  const int t = threadIdx.x;
  const int j0l = blockIdx.x * 64;
  const int c0 = blockIdx.y * 64;
  const int c_l = t >> 2;
  const int c = c0 + c_l;
  const int slab = j0l >> 12;
  const int hw0 = j0l & 4095;

  #pragma unroll
  for (int u = 0; u < 2; ++u) {
    int jp = u * 32 + (t & 3) * 8;
    u16x8 v = {0, 0, 0, 0, 0, 0, 0, 0};
    if (c < 392)
      v = *(const u16x8*)(att + (size_t)slab * 1605632 + (size_t)c * 4096 + hw0 + jp);
    #pragma unroll
    for (int i = 0; i < 8; ++i) ts[jp + i][c_l] = v[i];
  }
  __syncthreads();
  const int j_l = t >> 2;
  #pragma unroll
  for (int u = 0; u < 2; ++u) {
    int cp = u * 32 + (t & 3) * 8;
    u16x8 w;
    #pragma unroll
    for (int i = 0; i < 8; ++i) w[i] = ts[j_l][cp + i];
    int cg = c0 + cp;
    if (cg < 416) *(u16x8*)(aout + (size_t)(j0l + j_l) * 416 + cg) = w;
  }
}

// ---------------------------------------------------------------------------
// per-row sum/sumsq over 416 cols (pad cols are zero). One wave per row.
__global__ __launch_bounds__(256) void k_rowstats(const u16* __restrict__ buf,
                                                  float* __restrict__ sum, float* __restrict__ sq)
{
  const int t = threadIdx.x;
  const int lane = t & 63;
  const int row = blockIdx.x * 4 + (t >> 6);
  float s = 0.f, q = 0.f;
  if (lane < 52) {
    u16x8 v = *(const u16x8*)(buf + (size_t)row * 416 + lane * 8);
    #pragma unroll
    for (int i = 0; i < 8; ++i) { float f = bf2f(v[i]); s += f; q += f * f; }
  }
  #pragma unroll
  for (int d = 1; d < 64; d <<= 1) { s += __shfl_xor(s, d); q += __shfl_xor(q, d); }
  if (lane == 0) { sum[row] = s; sq[row] = q; }
}

// ---------------------------------------------------------------------------
// qkv GEMM (LN1 folded) + elementwise attention -> NCHW att (unchanged, R4)
__global__ __launch_bounds__(256, 2) void k_qkv(
    const u16* __restrict__ xt, const u16* __restrict__ w1p,
    const float* __restrict__ wsum1, const float* __restrict__ cb1,
    const float* __restrict__ sum1, const float* __restrict__ sq1,
    const void* __restrict__ relb, const int* __restrict__ dflag,
    u16* __restrict__ attout)
{
  __shared__ __align__(16) u16 lsA[2 * 4096];
  __shared__ __align__(16) u16 lsB[2 * 6144];
  const int flag = *dflag;
  const int t = threadIdx.x;
  const int wid = t >> 6, lane = t & 63;
  const int l15 = lane & 15, quad = lane >> 4;
  const int bid = blockIdx.x;
  const int h = (bid >> 3) & 7;
  const int jl0 = ((bid & 7) + ((bid >> 6) << 3)) * 128;

  const u16* ga0 = xt + (size_t)(jl0 + (t >> 2)) * 416 + (t & 3) * 8;
  const u16* ga1 = ga0 + (size_t)64 * 416;
  const int orow = t >> 2, kpart = (t & 3) * 8;
  const u16* gbq = w1p + (size_t)(h * 49 + orow) * 416 + kpart;
  const u16* gbk = w1p + (size_t)(392 + h * 49 + orow) * 416 + kpart;
  const u16* gbv = w1p + (size_t)(784 + h * 49 + orow) * 416 + kpart;

  f32x4 zero4 = {0.f, 0.f, 0.f, 0.f};
  f32x4 accq[2][4], acck[2][4], accv[2][4];
  #pragma unroll
  for (int a = 0; a < 2; ++a)
    #pragma unroll
    for (int b2 = 0; b2 < 4; ++b2) { accq[a][b2] = zero4; acck[a][b2] = zero4; accv[a][b2] = zero4; }

  auto stage = [&](int b, int kk) {
    u16* A = lsA + b * 4096;
    u16* B = lsB + b * 6144;
    gload16(ga0 + kk, A + t * 8);
    gload16(ga1 + kk, A + 2048 + t * 8);
    gload16(gbq + kk, B + t * 8);
    gload16(gbk + kk, B + 2048 + t * 8);
    gload16(gbv + kk, B + 4096 + t * 8);
  };

  stage(0, 0);
  int cur = 0;
  for (int it = 0; it < 13; ++it) {
    if (it < 12) { stage(cur ^ 1, (it + 1) * 32); WAIT_VM(5); }
    else WAIT_VM(0);
    SBAR();
    SCHED_FENCE();
    const u16* A = lsA + cur * 4096;
    const u16* B = lsB + cur * 6144;
    short8 af0 = *(const short8*)(A + ((wid * 32 + l15) * 32 + quad * 8));
    short8 af1 = *(const short8*)(A + ((wid * 32 + 16 + l15) * 32 + quad * 8));
    #pragma unroll
    for (int of = 0; of < 4; ++of) {
      const int bo_ = (of * 16 + l15) * 32 + quad * 8;
      short8 bq = *(const short8*)(B + bo_);
      short8 bk = *(const short8*)(B + 2048 + bo_);
      short8 bv = *(const short8*)(B + 4096 + bo_);
      accq[0][of] = mfma16(af0, bq, accq[0][of]);
      accq[1][of] = mfma16(af1, bq, accq[1][of]);
      acck[0][of] = mfma16(af0, bk, acck[0][of]);
      acck[1][of] = mfma16(af1, bk, acck[1][of]);
      accv[0][of] = mfma16(af0, bv, accv[0][of]);
      accv[1][of] = mfma16(af1, bv, accv[1][of]);
    }
    SCHED_FENCE();
    SBAR();
    cur ^= 1;
  }

  const float scale = 1.f / 7.f;
  float cq[4], wq[4], ck[4], wk[4], cv[4], wv_[4], bo[4];
  int dl[4];
  #pragma unroll
  for (int of = 0; of < 4; ++of) {
    int d = of * 16 + l15; dl[of] = d;
    int rq = h * 49 + d, rk = 392 + h * 49 + d, rv = 784 + h * 49 + d;
    wq[of] = wsum1[rq]; cq[of] = cb1[rq];
    wk[of] = wsum1[rk]; ck[of] = cb1[rk];
    wv_[of] = wsum1[rv]; cv[of] = cb1[rv];
    bo[of] = (d < 49) ? loadx(relb, h * 49 + d, flag) : 0.f;
  }
  #pragma unroll
  for (int jf = 0; jf < 2; ++jf) {
    #pragma unroll
    for (int r = 0; r < 4; ++r) {
      int jl = jl0 + wid * 32 + jf * 16 + quad * 4 + r;
      float mu = sum1[jl] * (1.f / 392.f);
      float var = sq1[jl] * (1.f / 392.f) - mu * mu;
      float rs = rsqrtf(fmaxf(var, 0.f) + 1e-5f);
      float sv[4], vv[4];
      float mx = -1e30f;
      #pragma unroll
      for (int of = 0; of < 4; ++of) {
        float qv = rs * accq[jf][of][r] + cq[of] - mu * rs * wq[of];
        float kv = rs * acck[jf][of][r] + ck[of] - mu * rs * wk[of];
        float s = (dl[of] < 49) ? (qv * scale * kv + bo[of]) : -1e30f;
        sv[of] = s; mx = fmaxf(mx, s);
        vv[of] = rs * accv[jf][of][r] + cv[of] - mu * rs * wv_[of];
      }
      #pragma unroll
      for (int d2 = 1; d2 < 16; d2 <<= 1) mx = fmaxf(mx, __shfl_xor(mx, d2));
      float sum = 0.f;
      #pragma unroll
      for (int of = 0; of < 4; ++of) { float e = __expf(sv[of] - mx); sv[of] = e; sum += e; }
      #pragma unroll
      for (int d2 = 1; d2 < 16; d2 <<= 1) sum += __shfl_xor(sum, d2);
      float inv = 1.f / sum;
      int pos = jl & 4095, slab = jl >> 12;
      size_t base = (size_t)slab * 1605632 + (size_t)h * 200704 + (size_t)pos * 49;
      #pragma unroll
      for (int of = 0; of < 4; ++of) {
        if (dl[of] < 49) attout[base + dl[of]] = f2bf(sv[of] * inv * vv[of]);
      }
    }
  }
}

// ===========================================================================
// Wide-N GEMM core pieces (512 threads, BM=128, BN=512, BK=32).
// 8 waves arranged 2(M) x 4(N); per-wave 64x128 = acc[4][8].
// LDS frag-major: A 8 frags x 1KB, B 32 frags x 1KB; lane-linear ds_read_b128
// (conflict-free). A staged from row-major global via per-lane src permute;
// B staged from pre-repacked frag-major weights. Traffic: A read ONCE per
// dispatch (y=1 for proj/fc2), B is L2-resident (<2MB).
// ===========================================================================

// proj GEMM + bias + residual(xt) -> x2t (N=512 covers all 416 padded cols)
__global__ __launch_bounds__(512, 2) void k_proj(
    const u16* __restrict__ aout, const u16* __restrict__ wppf,
    const void* __restrict__ projb, const int* __restrict__ dflag,
    const u16* __restrict__ xt, u16* __restrict__ x2t)
{
  __shared__ __align__(16) u16 lsA[3 * 4096];
  __shared__ __align__(16) u16 lsB[3 * 16384];
  const int flag = *dflag;
  const int t = threadIdx.x;
  const int w = t >> 6, lane = t & 63;
  const int l15 = lane & 15, quad = (lane >> 4) & 3;
  const int jl0 = blockIdx.x * 128;
  const int NK = 13;

  const u16* gA = aout + (size_t)(jl0 + (t >> 6) * 16 + l15) * 416 + quad * 8;
  const u16* gB = wppf + (size_t)(t >> 6) * NK * 512 + lane * 8;

  f32x4 zero4 = {0.f, 0.f, 0.f, 0.f};
  f32x4 acc[4][8];
  #pragma unroll
  for (int m = 0; m < 4; ++m)
    #pragma unroll
    for (int n = 0; n < 8; ++n) acc[m][n] = zero4;

  auto stage = [&](int b, int ks) {
    gload16(gA + ks * 32, lsA + b * 4096 + t * 8);
    #pragma unroll
    for (int c = 0; c < 4; ++c)
      gload16(gB + ((size_t)c * 8 * NK + ks) * 512,
              lsB + b * 16384 + (c * 8 + w) * 512 + lane * 8);
  };

  stage(0, 0); stage(1, 1);
  int bc = 0, bs = 2;
  for (int ks = 0; ks < NK; ++ks) {
    if (ks + 2 < NK) { stage(bs, ks + 2); WAIT_VM(10); }
    else if (ks + 1 < NK) WAIT_VM(5);
    else WAIT_VM(0);
    SBAR();
    SCHED_FENCE();
    const u16* A = lsA + bc * 4096;
    const u16* B = lsB + bc * 16384;
    short8 af[4];
    #pragma unroll
    for (int m = 0; m < 4; ++m)
      af[m] = *(const short8*)(A + ((w >> 2) * 4 + m) * 512 + lane * 8);
    #pragma unroll
    for (int n = 0; n < 8; ++n) {
      short8 bf = *(const short8*)(B + ((w & 3) * 8 + n) * 512 + lane * 8);
      #pragma unroll
      for (int m = 0; m < 4; ++m) acc[m][n] = mfma16(af[m], bf, acc[m][n]);
    }
    SCHED_FENCE();
    SBAR();
    bc = (bc + 1 == 3) ? 0 : bc + 1;
    bs = (bs + 1 == 3) ? 0 : bs + 1;
  }

  float pb[8]; int og[8];
  #pragma unroll
  for (int n = 0; n < 8; ++n) {
    int o = (w & 3) * 128 + n * 16 + l15; og[n] = o;
    pb[n] = (o < 392) ? loadx(projb, o, flag) : 0.f;
  }
  const int row0 = jl0 + (w >> 2) * 64;
  #pragma unroll
  for (int m = 0; m < 4; ++m) {
    #pragma unroll
    for (int r = 0; r < 4; ++r) {
      int jl = row0 + m * 16 + quad * 4 + r;
      #pragma unroll
      for (int n = 0; n < 8; ++n) {
        int o = og[n];
        if (o < 392) {
          float val = acc[m][n][r] + pb[n] + bf2f(xt[(size_t)jl * 416 + o]);
          x2t[(size_t)jl * 416 + o] = f2bf(val);
        } else if (o < 416) {
          x2t[(size_t)jl * 416 + o] = 0;
        }
      }
    }
  }
}

// fc1 GEMM (LN2 folded) + exact gelu -> ut. y-block covers o0=y*512 (2048 pad).
__global__ __launch_bounds__(512, 2) void k_fc1(
    const u16* __restrict__ x2t, const u16* __restrict__ w3pf,
    const float* __restrict__ wsum3, const float* __restrict__ cb3,
    const float* __restrict__ sum2, const float* __restrict__ sq2,
    u16* __restrict__ ut)
{
  __shared__ __align__(16) u16 lsA[3 * 4096];
  __shared__ __align__(16) u16 lsB[3 * 16384];
  const int t = threadIdx.x;
  const int w = t >> 6, lane = t & 63;
  const int l15 = lane & 15, quad = (lane >> 4) & 3;
  const int jl0 = blockIdx.x * 128;
  const int o0 = blockIdx.y * 512;
  const int NK = 13;

  const u16* gA = x2t + (size_t)(jl0 + (t >> 6) * 16 + l15) * 416 + quad * 8;
  const u16* gB = w3pf + ((size_t)(blockIdx.y * 32 + (t >> 6)) * NK) * 512 + lane * 8;

  f32x4 zero4 = {0.f, 0.f, 0.f, 0.f};
  f32x4 acc[4][8];
  #pragma unroll
  for (int m = 0; m < 4; ++m)
    #pragma unroll
    for (int n = 0; n < 8; ++n) acc[m][n] = zero4;

  auto stage = [&](int b, int ks) {
    gload16(gA + ks * 32, lsA + b * 4096 + t * 8);
    #pragma unroll
    for (int c = 0; c < 4; ++c)
      gload16(gB + ((size_t)c * 8 * NK + ks) * 512,
              lsB + b * 16384 + (c * 8 + w) * 512 + lane * 8);
  };

  stage(0, 0); stage(1, 1);
  int bc = 0, bs = 2;
  for (int ks = 0; ks < NK; ++ks) {
    if (ks + 2 < NK) { stage(bs, ks + 2); WAIT_VM(10); }
    else if (ks + 1 < NK) WAIT_VM(5);
    else WAIT_VM(0);
    SBAR();
    SCHED_FENCE();
    const u16* A = lsA + bc * 4096;
    const u16* B = lsB + bc * 16384;
    short8 af[4];
    #pragma unroll
    for (int m = 0; m < 4; ++m)
      af[m] = *(const short8*)(A + ((w >> 2) * 4 + m) * 512 + lane * 8);
    #pragma unroll
    for (int n = 0; n < 8; ++n) {
      short8 bf = *(const short8*)(B + ((w & 3) * 8 + n) * 512 + lane * 8);
      #pragma unroll
      for (int m = 0; m < 4; ++m) acc[m][n] = mfma16(af[m], bf, acc[m][n]);
    }
    SCHED_FENCE();
    SBAR();
    bc = (bc + 1 == 3) ? 0 : bc + 1;
    bs = (bs + 1 == 3) ? 0 : bs + 1;
  }

  float c3[8], w3[8]; int og[8];
  #pragma unroll
  for (int n = 0; n < 8; ++n) {
    int o = o0 + (w & 3) * 128 + n * 16 + l15; og[n] = o;
    c3[n] = cb3[o]; w3[n] = wsum3[o];
  }
  const int row0 = jl0 + (w >> 2) * 64;
  #pragma unroll
  for (int m = 0; m < 4; ++m) {
    #pragma unroll
    for (int r = 0; r < 4; ++r) {
      int jl = row0 + m * 16 + quad * 4 + r;
      float mu = sum2[jl] * (1.f / 392.f);
      float var = sq2[jl] * (1.f / 392.f) - mu * mu;
      float rs = rsqrtf(fmaxf(var, 0.f) + 1e-5f);
      #pragma unroll
      for (int n = 0; n < 8; ++n) {
        if (og[n] < 1568) {
          float u = rs * acc[m][n][r] + c3[n] - mu * rs * w3[n];
          float gl = 0.5f * u * (1.f + erff(u * 0.70710678118654752f));
          ut[(size_t)jl * 1568 + og[n]] = f2bf(gl);
        }
      }
    }
  }
}

// fc2 GEMM + bias + residual(x2) -> NCHW out. N=512 covers all 392 (A read ONCE).
__global__ __launch_bounds__(512, 2) void k_fc2(
    const u16* __restrict__ ut, const u16* __restrict__ wfpf,
    const void* __restrict__ fc2b, const int* __restrict__ dflag,
    const u16* __restrict__ x2t, void* __restrict__ outp, int jfg0)
{
  __shared__ __align__(16) u16 lsA[3 * 4096];
  __shared__ __align__(16) u16 lsB[3 * 16384];
  const int flag = *dflag;
  const int t = threadIdx.x;
  const int w = t >> 6, lane = t & 63;
  const int l15 = lane & 15, quad = (lane >> 4) & 3;
  const int jl0 = blockIdx.x * 128;
  const int NK = 49;

  const u16* gA = ut + (size_t)(jl0 + (t >> 6) * 16 + l15) * 1568 + quad * 8;
  const u16* gB = wfpf + (size_t)(t >> 6) * NK * 512 + lane * 8;

  f32x4 zero4 = {0.f, 0.f, 0.f, 0.f};
  f32x4 acc[4][8];
  #pragma unroll
  for (int m = 0; m < 4; ++m)
    #pragma unroll
    for (int n = 0; n < 8; ++n) acc[m][n] = zero4;

  auto stage = [&](int b, int ks) {
    gload16(gA + ks * 32, lsA + b * 4096 + t * 8);
    #pragma unroll
    for (int c = 0; c < 4; ++c)
      gload16(gB + ((size_t)c * 8 * NK + ks) * 512,
              lsB + b * 16384 + (c * 8 + w) * 512 + lane * 8);
  };

  stage(0, 0); stage(1, 1);
  int bc = 0, bs = 2;
  for (int ks = 0; ks < NK; ++ks) {
    if (ks + 2 < NK) { stage(bs, ks + 2); WAIT_VM(10); }
    else if (ks + 1 < NK) WAIT_VM(5);
    else WAIT_VM(0);
    SBAR();
    SCHED_FENCE();
    const u16* A = lsA + bc * 4096;
    const u16* B = lsB + bc * 16384;
    short8 af[4];
    #pragma unroll
    for (int m = 0; m < 4; ++m)
      af[m] = *(const short8*)(A + ((w >> 2) * 4 + m) * 512 + lane * 8);
    #pragma unroll
    for (int n = 0; n < 8; ++n) {
      short8 bf = *(const short8*)(B + ((w & 3) * 8 + n) * 512 + lane * 8);
      #pragma unroll
      for (int m = 0; m < 4; ++m) acc[m][n] = mfma16(af[m], bf, acc[m][n]);
    }
    SCHED_FENCE();
    SBAR();
    bc = (bc + 1 == 3) ? 0 : bc + 1;
    bs = (bs + 1 == 3) ? 0 : bs + 1;
  }

  float fb4[8]; int og[8];
  #pragma unroll
  for (int n = 0; n < 8; ++n) {
    int o = (w & 3) * 128 + n * 16 + l15; og[n] = o;
    fb4[n] = (o < 392) ? loadx(fc2b, o, flag) : 0.f;
  }
  const int row0 = jl0 + (w >> 2) * 64;
  #pragma unroll
  for (int m = 0; m < 4; ++m) {
    int jlbase = row0 + m * 16 + quad * 4;
    int jgbase = jfg0 + jlbase;
    int bslab = jgbase >> 12;
    int hw = jgbase & 4095;
    #pragma unroll
    for (int n = 0; n < 8; ++n) {
      if (og[n] < 392) {
        float v4[4];
        #pragma unroll
        for (int r = 0; r < 4; ++r)
          v4[r] = acc[m][n][r] + fb4[n] + bf2f(x2t[(size_t)(jlbase + r) * 416 + og[n]]);
        size_t obase = (((size_t)(bslab * 392 + og[n])) << 12) + hw;
        if (flag) {
          u16x4 pk;
          #pragma unroll
          for (int r = 0; r < 4; ++r) pk[r] = f2bf(v4[r]);
          *(u16x4*)((u16*)outp + obase) = pk;
        } else {
          f32x4 pk;
          #pragma unroll
          for (int r = 0; r < 4; ++r) pk[r] = v4[r];
          *(f32x4*)((float*)outp + obase) = pk;
        }
      }
    }
  }
}

// ---------------------------------------------------------------------------
extern "C" void kernel_launch(void* const* d_in, const int* in_sizes, int n_in,
                              void* d_out, int out_size, void* d_ws, size_t ws_size,
                              hipStream_t stream)
{
  if (n_in != 14 || in_sizes[0] != 16 * 392 * 64 * 64 || out_size != 16 * 392 * 64 * 64 ||
      in_sizes[3] != 3 * 392 * 392 || in_sizes[5] != 8 * 7 * 7 ||
      in_sizes[10] != 1568 * 392 || in_sizes[12] != 392 * 1568) {
    return;
  }

  const void* x     = d_in[0];
  const void* g1    = d_in[1];
  const void* b1    = d_in[2];
  const void* qkvw  = d_in[3];
  const void* qkvb  = d_in[4];
  const void* relb  = d_in[5];
  const void* projw = d_in[6];
  const void* projb = d_in[7];
  const void* g2    = d_in[8];
  const void* b2    = d_in[9];
  const void* fc1w  = d_in[10];
  const void* fc1b  = d_in[11];
  const void* fc2w  = d_in[12];
  const void* fc2b  = d_in[13];

  int S = 0, F = 0;
  {
    const int cand[8][2] = {{16,8},{16,4},{8,4},{8,2},{4,2},{4,1},{2,1},{1,1}};
    for (int i = 0; i < 8; ++i) {
      size_t nb = (size_t)cand[i][0] * 4096 * 416 * 2 * 3
                + (size_t)cand[i][1] * 4096 * 1568 * 2
                + (size_t)24 * 1024 * 1024;                 // weights + stats + slack
      if (nb <= ws_size) { S = cand[i][0]; F = cand[i][1]; break; }
    }
    if (S == 0) return;
  }

  char* wsb = (char*)d_ws;
  size_t off = 0;
  auto alloc = [&](size_t bytes) -> void* {
    void* p = wsb + off;
    off = (off + bytes + 255) & ~(size_t)255;
    return p;
  };
  int*  dflag = (int*)alloc(256);
  u16* xt    = (u16*)alloc((size_t)S * 4096 * 416 * 2);
  u16* aout  = (u16*)alloc((size_t)S * 4096 * 416 * 2);
  u16* x2t   = (u16*)alloc((size_t)S * 4096 * 416 * 2);
  u16* ut    = (u16*)alloc((size_t)F * 4096 * 1568 * 2);
  u16* w1p   = (u16*)alloc((size_t)1200 * 416 * 2);
  u16* w3r   = (u16*)alloc((size_t)2048 * 416 * 2);    // fc1 folded, row-major tmp
  u16* w3pf  = (u16*)alloc((size_t)2048 * 416 * 2);    // fc1 frag-major [128f][13ks][512]
  u16* wpr   = (u16*)alloc((size_t)512 * 416 * 2);     // proj row-major tmp
  u16* wppf  = (u16*)alloc((size_t)512 * 416 * 2);     // proj frag-major [32f][13ks][512]
  u16* wfr   = (u16*)alloc((size_t)512 * 1568 * 2);    // fc2 row-major tmp
  u16* wfpf  = (u16*)alloc((size_t)512 * 1568 * 2);    // fc2 frag-major [32f][49ks][512]
  float* wsum1 = (float*)alloc(1200 * 4);
  float* cb1   = (float*)alloc(1200 * 4);
  float* wsum3 = (float*)alloc(2048 * 4);
  float* cb3   = (float*)alloc(2048 * 4);
  float* sum1  = (float*)alloc((size_t)65536 * 4);
  float* sq1   = (float*)alloc((size_t)65536 * 4);
  float* sum2  = (float*)alloc((size_t)65536 * 4);
  float* sq2   = (float*)alloc((size_t)65536 * 4);

  u16* att = x2t;   // aliasing unchanged (dead before k_proj writes x2t)

  k_detect<<<1, 256, 0, stream>>>((const unsigned int*)x, dflag);

  k_prep_fold<<<1200, 64, 0, stream>>>(qkvw, g1, b1, qkvb, dflag, w1p, wsum1, cb1, 1176, 392, 416);
  k_prep_fold<<<2048, 64, 0, stream>>>(fc1w, g2, b2, fc1b, dflag, w3r, wsum3, cb3, 1568, 392, 416);
  k_prep_pad<<<(512 * 416 + 255) / 256, 256, 0, stream>>>(projw, dflag, wpr, 392, 392, 416, (long)512 * 416);
  k_prep_pad<<<(512 * 1568 + 255) / 256, 256, 0, stream>>>(fc2w, dflag, wfr, 392, 1568, 1568, (long)512 * 1568);
  k_repack<<<((2048 * 416 / 8) + 255) / 256, 256, 0, stream>>>(w3r, w3pf, 2048, 416);
  k_repack<<<((512 * 416 / 8) + 255) / 256, 256, 0, stream>>>(wpr, wppf, 512, 416);
  k_repack<<<((512 * 1568 / 8) + 255) / 256, 256, 0, stream>>>(wfr, wfpf, 512, 1568);

  for (int c0 = 0; c0 < 16; c0 += S) {
    const int jg0 = c0 * 4096;
    k_transpose<<<dim3(S * 64, 7), 256, 0, stream>>>(x, dflag, xt, jg0);
    k_rowstats<<<S * 1024, 256, 0, stream>>>(xt, sum1, sq1);
    k_qkv<<<dim3(S * 256), 256, 0, stream>>>(xt, w1p, wsum1, cb1, sum1, sq1, relb, dflag, att);
    k_att_tr<<<dim3(S * 64, 7), 256, 0, stream>>>(att, aout);
    k_proj<<<dim3(S * 32), 512, 0, stream>>>(aout, wppf, projb, dflag, xt, x2t);
    k_rowstats<<<S * 1024, 256, 0, stream>>>(x2t, sum2, sq2);
    for (int f0 = 0; f0 < S; f0 += F) {
      const int jfg0 = (c0 + f0) * 4096;
      const u16* x2sub = x2t + (size_t)f0 * 4096 * 416;
      k_fc1<<<dim3(F * 32, 4), 512, 0, stream>>>(x2sub, w3pf, wsum3, cb3,
                                                 sum2 + (size_t)f0 * 4096, sq2 + (size_t)f0 * 4096, ut);
      k_fc2<<<dim3(F * 32), 512, 0, stream>>>(ut, wfpf, fc2b, dflag, x2sub, d_out, jfg0);
    }
  }
}

// Round 7
// 809.314 us; speedup vs baseline: 1.1639x; 1.1639x over previous
//
#include <hip/hip_runtime.h>

typedef unsigned short u16;
typedef __attribute__((ext_vector_type(8))) short short8;
typedef __attribute__((ext_vector_type(8))) unsigned short u16x8;
typedef __attribute__((ext_vector_type(4))) unsigned short u16x4;
typedef __attribute__((ext_vector_type(4))) float f32x4;

#define DEVINL __device__ __forceinline__

DEVINL float bf2f(u16 v) { return __builtin_bit_cast(float, (unsigned int)v << 16); }
DEVINL u16 f2bf(float f) {
  unsigned int u = __builtin_bit_cast(unsigned int, f);
  u += 0x7fffu + ((u >> 16) & 1u);
  return (u16)(u >> 16);
}

// polymorphic scalar input load: flag=1 -> bf16, flag=0 -> f32
DEVINL float loadx(const void* p, size_t i, int flag) {
  return flag ? bf2f(((const u16*)p)[i]) : ((const float*)p)[i];
}

DEVINL f32x4 mfma16(short8 a, short8 b, f32x4 c) {
  return __builtin_amdgcn_mfma_f32_16x16x32_bf16(a, b, c, 0, 0, 0);
}

// async global->LDS, 16B per lane. LDS dest must be wave-uniform base + lane*16.
DEVINL void gload16(const u16* g, u16* l) {
  __builtin_amdgcn_global_load_lds(
      (const __attribute__((address_space(1))) unsigned int*)g,
      (__attribute__((address_space(3))) unsigned int*)l,
      16, 0, 0);
}

#define WAIT_VM(n) asm volatile("s_waitcnt vmcnt(" #n ")" ::: "memory")
#define SBAR() __builtin_amdgcn_s_barrier()
#define SCHED_FENCE() __builtin_amdgcn_sched_barrier(0)

// ---------------------------------------------------------------------------
// dtype detector (unchanged)
__global__ void k_detect(const unsigned int* __restrict__ xw, int* __restrict__ flag)
{
  const int t = threadIdx.x;
  int cnt = 0;
  for (int i = t; i < 4096; i += 256) {
    unsigned int w = xw[i];
    unsigned int h = w & 0xFFFFu;
    unsigned int e = (h >> 7) & 0xFFu;
    if (((h & 0x7FFFu) == 0u) || (e >= 117u && e <= 130u)) cnt++;
  }
  #pragma unroll
  for (int d = 1; d < 64; d <<= 1) cnt += __shfl_xor(cnt, d);
  __shared__ int acc[4];
  if ((t & 63) == 0) acc[t >> 6] = cnt;
  __syncthreads();
  if (t == 0) *flag = ((acc[0] + acc[1] + acc[2] + acc[3]) > 2048) ? 1 : 0;
}

// ---------------------------------------------------------------------------
// prep: W' = W * g (bf16), wsum[o] = sum_c W'[o,c], cb[o] = bias[o] + sum W*beta
__global__ void k_prep_fold(const void* __restrict__ w, const void* __restrict__ g,
                            const void* __restrict__ beta, const void* __restrict__ wbias,
                            const int* __restrict__ dflag,
                            u16* __restrict__ wp, float* __restrict__ wsum, float* __restrict__ cb,
                            int rows, int K, int KP)
{
  const int flag = *dflag;
  const int o = blockIdx.x;
  const int lane = threadIdx.x; // 64
  float ws = 0.f, c = 0.f;
  if (o < rows) {
    for (int k = lane; k < KP; k += 64) {
      u16 outv = 0;
      if (k < K) {
        float wv = loadx(w, (size_t)o * K + k, flag);
        float gv = loadx(g, k, flag);
        outv = f2bf(wv * gv);
        ws += bf2f(outv);
        c  += wv * loadx(beta, k, flag);
      }
      wp[(size_t)o * KP + k] = outv;
    }
  } else {
    for (int k = lane; k < KP; k += 64) wp[(size_t)o * KP + k] = 0;
  }
  #pragma unroll
  for (int d = 1; d < 64; d <<= 1) { ws += __shfl_xor(ws, d); c += __shfl_xor(c, d); }
  if (lane == 0) { wsum[o] = ws; cb[o] = (o < rows) ? (c + loadx(wbias, o, flag)) : 0.f; }
}

// zero-padded bf16 copy of a weight matrix (input f32 or bf16 per flag)
__global__ void k_prep_pad(const void* __restrict__ w, const int* __restrict__ dflag,
                           u16* __restrict__ wp, int rows, int K, int KP, long total)
{
  const int flag = *dflag;
  long i = (long)blockIdx.x * 256 + threadIdx.x;
  if (i >= total) return;
  int r = (int)(i / KP), c2 = (int)(i % KP);
  wp[i] = (r < rows && c2 < K) ? f2bf(loadx(w, (size_t)r * K + c2, flag)) : (u16)0;
}

// ---------------------------------------------------------------------------
// repack row-major padded [RP][KP] -> fragment-major:
// dst[(f*nK + ks)*512 + l*8 + j] = src[(f*16 + (l&15))*KP + ks*32 + ((l>>4)&3)*8 + j]
// One MFMA fragment = 512 contiguous u16, lane-linear (conflict-free ds_read_b128,
// and a valid lane-linear global_load_lds destination). Verified end-to-end in R6.
__global__ void k_repack(const u16* __restrict__ src, u16* __restrict__ dst, int RP, int KP)
{
  const int nK = KP / 32;
  long i = (long)blockIdx.x * 256 + threadIdx.x;   // one u16x8 each
  if (i * 8 >= (long)RP * KP) return;
  int l = (int)(i & 63);
  long fk = i >> 6;
  int ks = (int)(fk % nK), f = (int)(fk / nK);
  const u16* s = src + (size_t)(f * 16 + (l & 15)) * KP + ks * 32 + ((l >> 4) & 3) * 8;
  *(u16x8*)(dst + i * 8) = *(const u16x8*)s;
}

// ---------------------------------------------------------------------------
// transpose chunk of x [16][392][4096] -> xt [S*4096][416] bf16 (pad cols zeroed)
__global__ __launch_bounds__(256) void k_transpose(const void* __restrict__ xraw,
                                                   const int* __restrict__ dflag,
                                                   u16* __restrict__ xt, int jg0)
{
  __shared__ u16 ts[64][72];
  const int flag = *dflag;
  const int t = threadIdx.x;
  const int j0l = blockIdx.x * 64;
  const int j0g = jg0 + j0l;
  const int c0 = blockIdx.y * 64;
  const int c_l = t >> 2;
  const int c = c0 + c_l;
  const int bb = j0g >> 12;
  const int hw0 = j0g & 4095;

  #pragma unroll
  for (int u = 0; u < 2; ++u) {
    int jp = u * 32 + (t & 3) * 8;
    u16 vv[8] = {0, 0, 0, 0, 0, 0, 0, 0};
    if (c < 392) {
      size_t base = (((size_t)(bb * 392 + c)) << 12) + hw0 + jp;
      if (flag) {
        u16x8 v = *(const u16x8*)((const u16*)xraw + base);
        #pragma unroll
        for (int i = 0; i < 8; ++i) vv[i] = v[i];
      } else {
        const float* xf = (const float*)xraw + base;
        f32x4 a = *(const f32x4*)xf;
        f32x4 b = *(const f32x4*)(xf + 4);
        #pragma unroll
        for (int i = 0; i < 4; ++i) { vv[i] = f2bf(a[i]); vv[4 + i] = f2bf(b[i]); }
      }
    }
    #pragma unroll
    for (int i = 0; i < 8; ++i) ts[jp + i][c_l] = vv[i];
  }
  __syncthreads();
  const int j_l = t >> 2;
  #pragma unroll
  for (int u = 0; u < 2; ++u) {
    int cp = u * 32 + (t & 3) * 8;
    u16x8 w;
    #pragma unroll
    for (int i = 0; i < 8; ++i) w[i] = ts[j_l][cp + i];
    int cg = c0 + cp;
    if (cg < 416) *(u16x8*)(xt + (size_t)(j0l + j_l) * 416 + cg) = w;
  }
}

// ---------------------------------------------------------------------------
// transpose chunk-local attention output att [s][392][4096] -> aout [.][416]
__global__ __launch_bounds__(256) void k_att_tr(const u16* __restrict__ att,
                                                u16* __restrict__ aout)
{
  __shared__ u16 ts[64][72];
  const int t = threadIdx.x;
  const int j0l = blockIdx.x * 64;
  const int c0 = blockIdx.y * 64;
  const int c_l = t >> 2;
  const int c = c0 + c_l;
  const int slab = j0l >> 12;
  const int hw0 = j0l & 4095;

  #pragma unroll
  for (int u = 0; u < 2; ++u) {
    int jp = u * 32 + (t & 3) * 8;
    u16x8 v = {0, 0, 0, 0, 0, 0, 0, 0};
    if (c < 392)
      v = *(const u16x8*)(att + (size_t)slab * 1605632 + (size_t)c * 4096 + hw0 + jp);
    #pragma unroll
    for (int i = 0; i < 8; ++i) ts[jp + i][c_l] = v[i];
  }
  __syncthreads();
  const int j_l = t >> 2;
  #pragma unroll
  for (int u = 0; u < 2; ++u) {
    int cp = u * 32 + (t & 3) * 8;
    u16x8 w;
    #pragma unroll
    for (int i = 0; i < 8; ++i) w[i] = ts[j_l][cp + i];
    int cg = c0 + cp;
    if (cg < 416) *(u16x8*)(aout + (size_t)(j0l + j_l) * 416 + cg) = w;
  }
}

// ---------------------------------------------------------------------------
// per-row sum/sumsq over 416 cols (pad cols are zero). One wave per row.
__global__ __launch_bounds__(256) void k_rowstats(const u16* __restrict__ buf,
                                                  float* __restrict__ sum, float* __restrict__ sq)
{
  const int t = threadIdx.x;
  const int lane = t & 63;
  const int row = blockIdx.x * 4 + (t >> 6);
  float s = 0.f, q = 0.f;
  if (lane < 52) {
    u16x8 v = *(const u16x8*)(buf + (size_t)row * 416 + lane * 8);
    #pragma unroll
    for (int i = 0; i < 8; ++i) { float f = bf2f(v[i]); s += f; q += f * f; }
  }
  #pragma unroll
  for (int d = 1; d < 64; d <<= 1) { s += __shfl_xor(s, d); q += __shfl_xor(q, d); }
  if (lane == 0) { sum[row] = s; sq[row] = q; }
}

// ---------------------------------------------------------------------------
// qkv GEMM (LN1 folded) + elementwise attention -> NCHW att (unchanged, R4)
__global__ __launch_bounds__(256, 2) void k_qkv(
    const u16* __restrict__ xt, const u16* __restrict__ w1p,
    const float* __restrict__ wsum1, const float* __restrict__ cb1,
    const float* __restrict__ sum1, const float* __restrict__ sq1,
    const void* __restrict__ relb, const int* __restrict__ dflag,
    u16* __restrict__ attout)
{
  __shared__ __align__(16) u16 lsA[2 * 4096];
  __shared__ __align__(16) u16 lsB[2 * 6144];
  const int flag = *dflag;
  const int t = threadIdx.x;
  const int wid = t >> 6, lane = t & 63;
  const int l15 = lane & 15, quad = lane >> 4;
  const int bid = blockIdx.x;
  const int h = (bid >> 3) & 7;
  const int jl0 = ((bid & 7) + ((bid >> 6) << 3)) * 128;

  const u16* ga0 = xt + (size_t)(jl0 + (t >> 2)) * 416 + (t & 3) * 8;
  const u16* ga1 = ga0 + (size_t)64 * 416;
  const int orow = t >> 2, kpart = (t & 3) * 8;
  const u16* gbq = w1p + (size_t)(h * 49 + orow) * 416 + kpart;
  const u16* gbk = w1p + (size_t)(392 + h * 49 + orow) * 416 + kpart;
  const u16* gbv = w1p + (size_t)(784 + h * 49 + orow) * 416 + kpart;

  f32x4 zero4 = {0.f, 0.f, 0.f, 0.f};
  f32x4 accq[2][4], acck[2][4], accv[2][4];
  #pragma unroll
  for (int a = 0; a < 2; ++a)
    #pragma unroll
    for (int b2 = 0; b2 < 4; ++b2) { accq[a][b2] = zero4; acck[a][b2] = zero4; accv[a][b2] = zero4; }

  auto stage = [&](int b, int kk) {
    u16* A = lsA + b * 4096;
    u16* B = lsB + b * 6144;
    gload16(ga0 + kk, A + t * 8);
    gload16(ga1 + kk, A + 2048 + t * 8);
    gload16(gbq + kk, B + t * 8);
    gload16(gbk + kk, B + 2048 + t * 8);
    gload16(gbv + kk, B + 4096 + t * 8);
  };

  stage(0, 0);
  int cur = 0;
  for (int it = 0; it < 13; ++it) {
    if (it < 12) { stage(cur ^ 1, (it + 1) * 32); WAIT_VM(5); }
    else WAIT_VM(0);
    SBAR();
    SCHED_FENCE();
    const u16* A = lsA + cur * 4096;
    const u16* B = lsB + cur * 6144;
    short8 af0 = *(const short8*)(A + ((wid * 32 + l15) * 32 + quad * 8));
    short8 af1 = *(const short8*)(A + ((wid * 32 + 16 + l15) * 32 + quad * 8));
    #pragma unroll
    for (int of = 0; of < 4; ++of) {
      const int bo_ = (of * 16 + l15) * 32 + quad * 8;
      short8 bq = *(const short8*)(B + bo_);
      short8 bk = *(const short8*)(B + 2048 + bo_);
      short8 bv = *(const short8*)(B + 4096 + bo_);
      accq[0][of] = mfma16(af0, bq, accq[0][of]);
      accq[1][of] = mfma16(af1, bq, accq[1][of]);
      acck[0][of] = mfma16(af0, bk, acck[0][of]);
      acck[1][of] = mfma16(af1, bk, acck[1][of]);
      accv[0][of] = mfma16(af0, bv, accv[0][of]);
      accv[1][of] = mfma16(af1, bv, accv[1][of]);
    }
    SCHED_FENCE();
    SBAR();
    cur ^= 1;
  }

  const float scale = 1.f / 7.f;
  float cq[4], wq[4], ck[4], wk[4], cv[4], wv_[4], bo[4];
  int dl[4];
  #pragma unroll
  for (int of = 0; of < 4; ++of) {
    int d = of * 16 + l15; dl[of] = d;
    int rq = h * 49 + d, rk = 392 + h * 49 + d, rv = 784 + h * 49 + d;
    wq[of] = wsum1[rq]; cq[of] = cb1[rq];
    wk[of] = wsum1[rk]; ck[of] = cb1[rk];
    wv_[of] = wsum1[rv]; cv[of] = cb1[rv];
    bo[of] = (d < 49) ? loadx(relb, h * 49 + d, flag) : 0.f;
  }
  #pragma unroll
  for (int jf = 0; jf < 2; ++jf) {
    #pragma unroll
    for (int r = 0; r < 4; ++r) {
      int jl = jl0 + wid * 32 + jf * 16 + quad * 4 + r;
      float mu = sum1[jl] * (1.f / 392.f);
      float var = sq1[jl] * (1.f / 392.f) - mu * mu;
      float rs = rsqrtf(fmaxf(var, 0.f) + 1e-5f);
      float sv[4], vv[4];
      float mx = -1e30f;
      #pragma unroll
      for (int of = 0; of < 4; ++of) {
        float qv = rs * accq[jf][of][r] + cq[of] - mu * rs * wq[of];
        float kv = rs * acck[jf][of][r] + ck[of] - mu * rs * wk[of];
        float s = (dl[of] < 49) ? (qv * scale * kv + bo[of]) : -1e30f;
        sv[of] = s; mx = fmaxf(mx, s);
        vv[of] = rs * accv[jf][of][r] + cv[of] - mu * rs * wv_[of];
      }
      #pragma unroll
      for (int d2 = 1; d2 < 16; d2 <<= 1) mx = fmaxf(mx, __shfl_xor(mx, d2));
      float sum = 0.f;
      #pragma unroll
      for (int of = 0; of < 4; ++of) { float e = __expf(sv[of] - mx); sv[of] = e; sum += e; }
      #pragma unroll
      for (int d2 = 1; d2 < 16; d2 <<= 1) sum += __shfl_xor(sum, d2);
      float inv = 1.f / sum;
      int pos = jl & 4095, slab = jl >> 12;
      size_t base = (size_t)slab * 1605632 + (size_t)h * 200704 + (size_t)pos * 49;
      #pragma unroll
      for (int of = 0; of < 4; ++of) {
        if (dl[of] < 49) attout[base + dl[of]] = f2bf(sv[of] * inv * vv[of]);
      }
    }
  }
}

// ===========================================================================
// Frag-major GEMM core (256 threads, BM=128, BN=128, BK=32).
// 4 waves as 2(M) x 2(N); per-wave 64x64 = acc[4][4] (64 VGPR).
// LDS: 2 buf x (A 8 frags + B 8 frags) x 1KB = 32 KB -> 4 blocks/CU at
// __launch_bounds__(256,4). Frag-major layout (R6-verified): zero bank
// conflicts, lane-linear global_load_lds staging. 2-phase counted vmcnt.
// ===========================================================================

// proj GEMM + bias + residual(xt) -> x2t
__global__ __launch_bounds__(256, 4) void k_proj(
    const u16* __restrict__ aout, const u16* __restrict__ wppf,
    const void* __restrict__ projb, const int* __restrict__ dflag,
    const u16* __restrict__ xt, u16* __restrict__ x2t)
{
  __shared__ __align__(16) u16 lsA[2 * 4096];
  __shared__ __align__(16) u16 lsB[2 * 4096];
  const int flag = *dflag;
  const int t = threadIdx.x;
  const int w = t >> 6, lane = t & 63;
  const int l15 = lane & 15, quad = (lane >> 4) & 3;
  const int jl0 = blockIdx.x * 128;
  const int y = blockIdx.y, o0 = y * 128;
  const int NK = 13;
  const int wm = w >> 1, wn = w & 1;

  const u16* gA0 = aout + (size_t)(jl0 + w * 16 + l15) * 416 + quad * 8;
  const u16* gA1 = aout + (size_t)(jl0 + (4 + w) * 16 + l15) * 416 + quad * 8;
  const u16* gB0 = wppf + ((size_t)(y * 8 + w) * NK) * 512 + lane * 8;
  const u16* gB1 = wppf + ((size_t)(y * 8 + 4 + w) * NK) * 512 + lane * 8;

  f32x4 zero4 = {0.f, 0.f, 0.f, 0.f};
  f32x4 acc[4][4];
  #pragma unroll
  for (int m = 0; m < 4; ++m)
    #pragma unroll
    for (int n = 0; n < 4; ++n) acc[m][n] = zero4;

  auto stage = [&](int b, int ks) {
    gload16(gA0 + ks * 32, lsA + b * 4096 + w * 512 + lane * 8);
    gload16(gA1 + ks * 32, lsA + b * 4096 + (4 + w) * 512 + lane * 8);
    gload16(gB0 + (size_t)ks * 512, lsB + b * 4096 + w * 512 + lane * 8);
    gload16(gB1 + (size_t)ks * 512, lsB + b * 4096 + (4 + w) * 512 + lane * 8);
  };

  stage(0, 0);
  int cur = 0;
  for (int ks = 0; ks < NK; ++ks) {
    if (ks + 1 < NK) { stage(cur ^ 1, ks + 1); WAIT_VM(4); }
    else WAIT_VM(0);
    SBAR();
    SCHED_FENCE();
    const u16* A = lsA + cur * 4096;
    const u16* B = lsB + cur * 4096;
    short8 af[4];
    #pragma unroll
    for (int m = 0; m < 4; ++m)
      af[m] = *(const short8*)(A + (wm * 4 + m) * 512 + lane * 8);
    #pragma unroll
    for (int n = 0; n < 4; ++n) {
      short8 bf = *(const short8*)(B + (wn * 4 + n) * 512 + lane * 8);
      #pragma unroll
      for (int m = 0; m < 4; ++m) acc[m][n] = mfma16(af[m], bf, acc[m][n]);
    }
    SCHED_FENCE();
    SBAR();
    cur ^= 1;
  }

  float pb[4]; int og[4];
  #pragma unroll
  for (int n = 0; n < 4; ++n) {
    int o = o0 + wn * 64 + n * 16 + l15; og[n] = o;
    pb[n] = (o < 392) ? loadx(projb, o, flag) : 0.f;
  }
  const int row0 = jl0 + wm * 64;
  #pragma unroll
  for (int m = 0; m < 4; ++m) {
    #pragma unroll
    for (int r = 0; r < 4; ++r) {
      int jl = row0 + m * 16 + quad * 4 + r;
      #pragma unroll
      for (int n = 0; n < 4; ++n) {
        int o = og[n];
        if (o < 392) {
          float val = acc[m][n][r] + pb[n] + bf2f(xt[(size_t)jl * 416 + o]);
          x2t[(size_t)jl * 416 + o] = f2bf(val);
        } else if (o < 416) {
          x2t[(size_t)jl * 416 + o] = 0;
        }
      }
    }
  }
}

// fc1 GEMM (LN2 folded) + exact gelu -> ut
__global__ __launch_bounds__(256, 4) void k_fc1(
    const u16* __restrict__ x2t, const u16* __restrict__ w3pf,
    const float* __restrict__ wsum3, const float* __restrict__ cb3,
    const float* __restrict__ sum2, const float* __restrict__ sq2,
    u16* __restrict__ ut)
{
  __shared__ __align__(16) u16 lsA[2 * 4096];
  __shared__ __align__(16) u16 lsB[2 * 4096];
  const int t = threadIdx.x;
  const int w = t >> 6, lane = t & 63;
  const int l15 = lane & 15, quad = (lane >> 4) & 3;
  const int jl0 = blockIdx.x * 128;
  const int y = blockIdx.y, o0 = y * 128;
  const int NK = 13;
  const int wm = w >> 1, wn = w & 1;

  const u16* gA0 = x2t + (size_t)(jl0 + w * 16 + l15) * 416 + quad * 8;
  const u16* gA1 = x2t + (size_t)(jl0 + (4 + w) * 16 + l15) * 416 + quad * 8;
  const u16* gB0 = w3pf + ((size_t)(y * 8 + w) * NK) * 512 + lane * 8;
  const u16* gB1 = w3pf + ((size_t)(y * 8 + 4 + w) * NK) * 512 + lane * 8;

  f32x4 zero4 = {0.f, 0.f, 0.f, 0.f};
  f32x4 acc[4][4];
  #pragma unroll
  for (int m = 0; m < 4; ++m)
    #pragma unroll
    for (int n = 0; n < 4; ++n) acc[m][n] = zero4;

  auto stage = [&](int b, int ks) {
    gload16(gA0 + ks * 32, lsA + b * 4096 + w * 512 + lane * 8);
    gload16(gA1 + ks * 32, lsA + b * 4096 + (4 + w) * 512 + lane * 8);
    gload16(gB0 + (size_t)ks * 512, lsB + b * 4096 + w * 512 + lane * 8);
    gload16(gB1 + (size_t)ks * 512, lsB + b * 4096 + (4 + w) * 512 + lane * 8);
  };

  stage(0, 0);
  int cur = 0;
  for (int ks = 0; ks < NK; ++ks) {
    if (ks + 1 < NK) { stage(cur ^ 1, ks + 1); WAIT_VM(4); }
    else WAIT_VM(0);
    SBAR();
    SCHED_FENCE();
    const u16* A = lsA + cur * 4096;
    const u16* B = lsB + cur * 4096;
    short8 af[4];
    #pragma unroll
    for (int m = 0; m < 4; ++m)
      af[m] = *(const short8*)(A + (wm * 4 + m) * 512 + lane * 8);
    #pragma unroll
    for (int n = 0; n < 4; ++n) {
      short8 bf = *(const short8*)(B + (wn * 4 + n) * 512 + lane * 8);
      #pragma unroll
      for (int m = 0; m < 4; ++m) acc[m][n] = mfma16(af[m], bf, acc[m][n]);
    }
    SCHED_FENCE();
    SBAR();
    cur ^= 1;
  }

  float c3[4], w3[4]; int og[4];
  #pragma unroll
  for (int n = 0; n < 4; ++n) {
    int o = o0 + wn * 64 + n * 16 + l15; og[n] = o;
    c3[n] = cb3[o]; w3[n] = wsum3[o];
  }
  const int row0 = jl0 + wm * 64;
  #pragma unroll
  for (int m = 0; m < 4; ++m) {
    #pragma unroll
    for (int r = 0; r < 4; ++r) {
      int jl = row0 + m * 16 + quad * 4 + r;
      float mu = sum2[jl] * (1.f / 392.f);
      float var = sq2[jl] * (1.f / 392.f) - mu * mu;
      float rs = rsqrtf(fmaxf(var, 0.f) + 1e-5f);
      #pragma unroll
      for (int n = 0; n < 4; ++n) {
        if (og[n] < 1568) {
          float u = rs * acc[m][n][r] + c3[n] - mu * rs * w3[n];
          float gl = 0.5f * u * (1.f + erff(u * 0.70710678118654752f));
          ut[(size_t)jl * 1568 + og[n]] = f2bf(gl);
        }
      }
    }
  }
}

// fc2 GEMM + bias + residual(x2) -> final output in NCHW
__global__ __launch_bounds__(256, 4) void k_fc2(
    const u16* __restrict__ ut, const u16* __restrict__ wfpf,
    const void* __restrict__ fc2b, const int* __restrict__ dflag,
    const u16* __restrict__ x2t, void* __restrict__ outp, int jfg0)
{
  __shared__ __align__(16) u16 lsA[2 * 4096];
  __shared__ __align__(16) u16 lsB[2 * 4096];
  const int flag = *dflag;
  const int t = threadIdx.x;
  const int w = t >> 6, lane = t & 63;
  const int l15 = lane & 15, quad = (lane >> 4) & 3;
  const int jl0 = blockIdx.x * 128;
  const int y = blockIdx.y, o0 = y * 128;
  const int NK = 49;
  const int wm = w >> 1, wn = w & 1;

  const u16* gA0 = ut + (size_t)(jl0 + w * 16 + l15) * 1568 + quad * 8;
  const u16* gA1 = ut + (size_t)(jl0 + (4 + w) * 16 + l15) * 1568 + quad * 8;
  const u16* gB0 = wfpf + ((size_t)(y * 8 + w) * NK) * 512 + lane * 8;
  const u16* gB1 = wfpf + ((size_t)(y * 8 + 4 + w) * NK) * 512 + lane * 8;

  f32x4 zero4 = {0.f, 0.f, 0.f, 0.f};
  f32x4 acc[4][4];
  #pragma unroll
  for (int m = 0; m < 4; ++m)
    #pragma unroll
    for (int n = 0; n < 4; ++n) acc[m][n] = zero4;

  auto stage = [&](int b, int ks) {
    gload16(gA0 + ks * 32, lsA + b * 4096 + w * 512 + lane * 8);
    gload16(gA1 + ks * 32, lsA + b * 4096 + (4 + w) * 512 + lane * 8);
    gload16(gB0 + (size_t)ks * 512, lsB + b * 4096 + w * 512 + lane * 8);
    gload16(gB1 + (size_t)ks * 512, lsB + b * 4096 + (4 + w) * 512 + lane * 8);
  };

  stage(0, 0);
  int cur = 0;
  for (int ks = 0; ks < NK; ++ks) {
    if (ks + 1 < NK) { stage(cur ^ 1, ks + 1); WAIT_VM(4); }
    else WAIT_VM(0);
    SBAR();
    SCHED_FENCE();
    const u16* A = lsA + cur * 4096;
    const u16* B = lsB + cur * 4096;
    short8 af[4];
    #pragma unroll
    for (int m = 0; m < 4; ++m)
      af[m] = *(const short8*)(A + (wm * 4 + m) * 512 + lane * 8);
    #pragma unroll
    for (int n = 0; n < 4; ++n) {
      short8 bf = *(const short8*)(B + (wn * 4 + n) * 512 + lane * 8);
      #pragma unroll
      for (int m = 0; m < 4; ++m) acc[m][n] = mfma16(af[m], bf, acc[m][n]);
    }
    SCHED_FENCE();
    SBAR();
    cur ^= 1;
  }

  float fb4[4]; int og[4];
  #pragma unroll
  for (int n = 0; n < 4; ++n) {
    int o = o0 + wn * 64 + n * 16 + l15; og[n] = o;
    fb4[n] = (o < 392) ? loadx(fc2b, o, flag) : 0.f;
  }
  const int row0 = jl0 + wm * 64;
  #pragma unroll
  for (int m = 0; m < 4; ++m) {
    int jlbase = row0 + m * 16 + quad * 4;
    int jgbase = jfg0 + jlbase;
    int bslab = jgbase >> 12;
    int hw = jgbase & 4095;
    #pragma unroll
    for (int n = 0; n < 4; ++n) {
      if (og[n] < 392) {
        float v4[4];
        #pragma unroll
        for (int r = 0; r < 4; ++r)
          v4[r] = acc[m][n][r] + fb4[n] + bf2f(x2t[(size_t)(jlbase + r) * 416 + og[n]]);
        size_t obase = (((size_t)(bslab * 392 + og[n])) << 12) + hw;
        if (flag) {
          u16x4 pk;
          #pragma unroll
          for (int r = 0; r < 4; ++r) pk[r] = f2bf(v4[r]);
          *(u16x4*)((u16*)outp + obase) = pk;
        } else {
          f32x4 pk;
          #pragma unroll
          for (int r = 0; r < 4; ++r) pk[r] = v4[r];
          *(f32x4*)((float*)outp + obase) = pk;
        }
      }
    }
  }
}

// ---------------------------------------------------------------------------
extern "C" void kernel_launch(void* const* d_in, const int* in_sizes, int n_in,
                              void* d_out, int out_size, void* d_ws, size_t ws_size,
                              hipStream_t stream)
{
  if (n_in != 14 || in_sizes[0] != 16 * 392 * 64 * 64 || out_size != 16 * 392 * 64 * 64 ||
      in_sizes[3] != 3 * 392 * 392 || in_sizes[5] != 8 * 7 * 7 ||
      in_sizes[10] != 1568 * 392 || in_sizes[12] != 392 * 1568) {
    return;
  }

  const void* x     = d_in[0];
  const void* g1    = d_in[1];
  const void* b1    = d_in[2];
  const void* qkvw  = d_in[3];
  const void* qkvb  = d_in[4];
  const void* relb  = d_in[5];
  const void* projw = d_in[6];
  const void* projb = d_in[7];
  const void* g2    = d_in[8];
  const void* b2    = d_in[9];
  const void* fc1w  = d_in[10];
  const void* fc1b  = d_in[11];
  const void* fc2w  = d_in[12];
  const void* fc2b  = d_in[13];

  int S = 0, F = 0;
  {
    const int cand[8][2] = {{16,8},{16,4},{8,4},{8,2},{4,2},{4,1},{2,1},{1,1}};
    for (int i = 0; i < 8; ++i) {
      size_t nb = (size_t)cand[i][0] * 4096 * 416 * 2 * 3
                + (size_t)cand[i][1] * 4096 * 1568 * 2
                + (size_t)24 * 1024 * 1024;                 // weights + stats + slack
      if (nb <= ws_size) { S = cand[i][0]; F = cand[i][1]; break; }
    }
    if (S == 0) return;
  }

  char* wsb = (char*)d_ws;
  size_t off = 0;
  auto alloc = [&](size_t bytes) -> void* {
    void* p = wsb + off;
    off = (off + bytes + 255) & ~(size_t)255;
    return p;
  };
  int*  dflag = (int*)alloc(256);
  u16* xt    = (u16*)alloc((size_t)S * 4096 * 416 * 2);
  u16* aout  = (u16*)alloc((size_t)S * 4096 * 416 * 2);
  u16* x2t   = (u16*)alloc((size_t)S * 4096 * 416 * 2);
  u16* ut    = (u16*)alloc((size_t)F * 4096 * 1568 * 2);
  u16* w1p   = (u16*)alloc((size_t)1200 * 416 * 2);
  u16* w3r   = (u16*)alloc((size_t)2048 * 416 * 2);    // fc1 folded, row-major tmp
  u16* w3pf  = (u16*)alloc((size_t)2048 * 416 * 2);    // fc1 frag-major
  u16* wpr   = (u16*)alloc((size_t)512 * 416 * 2);     // proj row-major tmp
  u16* wppf  = (u16*)alloc((size_t)512 * 416 * 2);     // proj frag-major
  u16* wfr   = (u16*)alloc((size_t)512 * 1568 * 2);    // fc2 row-major tmp
  u16* wfpf  = (u16*)alloc((size_t)512 * 1568 * 2);    // fc2 frag-major
  float* wsum1 = (float*)alloc(1200 * 4);
  float* cb1   = (float*)alloc(1200 * 4);
  float* wsum3 = (float*)alloc(2048 * 4);
  float* cb3   = (float*)alloc(2048 * 4);
  float* sum1  = (float*)alloc((size_t)65536 * 4);
  float* sq1   = (float*)alloc((size_t)65536 * 4);
  float* sum2  = (float*)alloc((size_t)65536 * 4);
  float* sq2   = (float*)alloc((size_t)65536 * 4);

  u16* att = x2t;   // aliasing unchanged (dead before k_proj writes x2t)

  k_detect<<<1, 256, 0, stream>>>((const unsigned int*)x, dflag);

  k_prep_fold<<<1200, 64, 0, stream>>>(qkvw, g1, b1, qkvb, dflag, w1p, wsum1, cb1, 1176, 392, 416);
  k_prep_fold<<<2048, 64, 0, stream>>>(fc1w, g2, b2, fc1b, dflag, w3r, wsum3, cb3, 1568, 392, 416);
  k_prep_pad<<<(512 * 416 + 255) / 256, 256, 0, stream>>>(projw, dflag, wpr, 392, 392, 416, (long)512 * 416);
  k_prep_pad<<<(512 * 1568 + 255) / 256, 256, 0, stream>>>(fc2w, dflag, wfr, 392, 1568, 1568, (long)512 * 1568);
  k_repack<<<((2048 * 416 / 8) + 255) / 256, 256, 0, stream>>>(w3r, w3pf, 2048, 416);
  k_repack<<<((512 * 416 / 8) + 255) / 256, 256, 0, stream>>>(wpr, wppf, 512, 416);
  k_repack<<<((512 * 1568 / 8) + 255) / 256, 256, 0, stream>>>(wfr, wfpf, 512, 1568);

  for (int c0 = 0; c0 < 16; c0 += S) {
    const int jg0 = c0 * 4096;
    k_transpose<<<dim3(S * 64, 7), 256, 0, stream>>>(x, dflag, xt, jg0);
    k_rowstats<<<S * 1024, 256, 0, stream>>>(xt, sum1, sq1);
    k_qkv<<<dim3(S * 256), 256, 0, stream>>>(xt, w1p, wsum1, cb1, sum1, sq1, relb, dflag, att);
    k_att_tr<<<dim3(S * 64, 7), 256, 0, stream>>>(att, aout);
    k_proj<<<dim3(S * 32, 4), 256, 0, stream>>>(aout, wppf, projb, dflag, xt, x2t);
    k_rowstats<<<S * 1024, 256, 0, stream>>>(x2t, sum2, sq2);
    for (int f0 = 0; f0 < S; f0 += F) {
      const int jfg0 = (c0 + f0) * 4096;
      const u16* x2sub = x2t + (size_t)f0 * 4096 * 416;
      k_fc1<<<dim3(F * 32, 13), 256, 0, stream>>>(x2sub, w3pf, wsum3, cb3,
                                                  sum2 + (size_t)f0 * 4096, sq2 + (size_t)f0 * 4096, ut);
      k_fc2<<<dim3(F * 32, 4), 256, 0, stream>>>(ut, wfpf, fc2b, dflag, x2sub, d_out, jfg0);
    }
  }
}

// Round 8
// 806.859 us; speedup vs baseline: 1.1674x; 1.0030x over previous
//
#include <hip/hip_runtime.h>

typedef unsigned short u16;
typedef __attribute__((ext_vector_type(8))) short short8;
typedef __attribute__((ext_vector_type(8))) unsigned short u16x8;
typedef __attribute__((ext_vector_type(4))) unsigned short u16x4;
typedef __attribute__((ext_vector_type(4))) float f32x4;

#define DEVINL __device__ __forceinline__

DEVINL float bf2f(u16 v) { return __builtin_bit_cast(float, (unsigned int)v << 16); }
DEVINL u16 f2bf(float f) {
  unsigned int u = __builtin_bit_cast(unsigned int, f);
  u += 0x7fffu + ((u >> 16) & 1u);
  return (u16)(u >> 16);
}

// polymorphic scalar input load: flag=1 -> bf16, flag=0 -> f32
DEVINL float loadx(const void* p, size_t i, int flag) {
  return flag ? bf2f(((const u16*)p)[i]) : ((const float*)p)[i];
}

DEVINL f32x4 mfma16(short8 a, short8 b, f32x4 c) {
  return __builtin_amdgcn_mfma_f32_16x16x32_bf16(a, b, c, 0, 0, 0);
}

// async global->LDS, 16B per lane. LDS dest must be wave-uniform base + lane*16.
DEVINL void gload16(const u16* g, u16* l) {
  __builtin_amdgcn_global_load_lds(
      (const __attribute__((address_space(1))) unsigned int*)g,
      (__attribute__((address_space(3))) unsigned int*)l,
      16, 0, 0);
}

#define WAIT_VM(n) asm volatile("s_waitcnt vmcnt(" #n ")" ::: "memory")
#define SBAR() __builtin_amdgcn_s_barrier()
#define SCHED_FENCE() __builtin_amdgcn_sched_barrier(0)

// ---------------------------------------------------------------------------
// dtype detector (unchanged)
__global__ void k_detect(const unsigned int* __restrict__ xw, int* __restrict__ flag)
{
  const int t = threadIdx.x;
  int cnt = 0;
  for (int i = t; i < 4096; i += 256) {
    unsigned int w = xw[i];
    unsigned int h = w & 0xFFFFu;
    unsigned int e = (h >> 7) & 0xFFu;
    if (((h & 0x7FFFu) == 0u) || (e >= 117u && e <= 130u)) cnt++;
  }
  #pragma unroll
  for (int d = 1; d < 64; d <<= 1) cnt += __shfl_xor(cnt, d);
  __shared__ int acc[4];
  if ((t & 63) == 0) acc[t >> 6] = cnt;
  __syncthreads();
  if (t == 0) *flag = ((acc[0] + acc[1] + acc[2] + acc[3]) > 2048) ? 1 : 0;
}

// ---------------------------------------------------------------------------
// prep: W' = W * g (bf16), wsum[o] = sum_c W'[o,c], cb[o] = bias[o] + sum W*beta
__global__ void k_prep_fold(const void* __restrict__ w, const void* __restrict__ g,
                            const void* __restrict__ beta, const void* __restrict__ wbias,
                            const int* __restrict__ dflag,
                            u16* __restrict__ wp, float* __restrict__ wsum, float* __restrict__ cb,
                            int rows, int K, int KP)
{
  const int flag = *dflag;
  const int o = blockIdx.x;
  const int lane = threadIdx.x; // 64
  float ws = 0.f, c = 0.f;
  if (o < rows) {
    for (int k = lane; k < KP; k += 64) {
      u16 outv = 0;
      if (k < K) {
        float wv = loadx(w, (size_t)o * K + k, flag);
        float gv = loadx(g, k, flag);
        outv = f2bf(wv * gv);
        ws += bf2f(outv);
        c  += wv * loadx(beta, k, flag);
      }
      wp[(size_t)o * KP + k] = outv;
    }
  } else {
    for (int k = lane; k < KP; k += 64) wp[(size_t)o * KP + k] = 0;
  }
  #pragma unroll
  for (int d = 1; d < 64; d <<= 1) { ws += __shfl_xor(ws, d); c += __shfl_xor(c, d); }
  if (lane == 0) { wsum[o] = ws; cb[o] = (o < rows) ? (c + loadx(wbias, o, flag)) : 0.f; }
}

// zero-padded bf16 copy of a weight matrix (input f32 or bf16 per flag)
__global__ void k_prep_pad(const void* __restrict__ w, const int* __restrict__ dflag,
                           u16* __restrict__ wp, int rows, int K, int KP, long total)
{
  const int flag = *dflag;
  long i = (long)blockIdx.x * 256 + threadIdx.x;
  if (i >= total) return;
  int r = (int)(i / KP), c2 = (int)(i % KP);
  wp[i] = (r < rows && c2 < K) ? f2bf(loadx(w, (size_t)r * K + c2, flag)) : (u16)0;
}

// ---------------------------------------------------------------------------
// repack row-major padded [RP][KP] -> fragment-major:
// dst[(f*nK + ks)*512 + l*8 + j] = src[(f*16 + (l&15))*KP + ks*32 + ((l>>4)&3)*8 + j]
// One MFMA fragment = 512 contiguous u16, lane-linear (conflict-free ds_read_b128,
// and a valid lane-linear global_load_lds destination). Verified end-to-end in R6.
__global__ void k_repack(const u16* __restrict__ src, u16* __restrict__ dst, int RP, int KP)
{
  const int nK = KP / 32;
  long i = (long)blockIdx.x * 256 + threadIdx.x;   // one u16x8 each
  if (i * 8 >= (long)RP * KP) return;
  int l = (int)(i & 63);
  long fk = i >> 6;
  int ks = (int)(fk % nK), f = (int)(fk / nK);
  const u16* s = src + (size_t)(f * 16 + (l & 15)) * KP + ks * 32 + ((l >> 4) & 3) * 8;
  *(u16x8*)(dst + i * 8) = *(const u16x8*)s;
}

// ---------------------------------------------------------------------------
// repack folded qkv weights w1p [1176+pad][416] -> per-head frag-major
// w1f[h][frag=s*4+of][ks][512], 8 heads x 12 frags x 13 ks. Fragment rows
// of*16+(l&15); rows >=49 within a head's section are ZERO (replaces the
// old masked-garbage overrun past the 49-row head boundary).
__global__ void k_repack_qkv(const u16* __restrict__ w1p, u16* __restrict__ w1f)
{
  long i = (long)blockIdx.x * 256 + threadIdx.x;   // one u16x8 each
  if (i >= 79872) return;                           // 8*12*13*64
  int l = (int)(i & 63);
  long r = i >> 6;
  int ks = (int)(r % 13);
  long hf = r / 13;
  int frag = (int)(hf % 12), h = (int)(hf / 12);
  int s = frag >> 2, of = frag & 3;
  int rowInSec = of * 16 + (l & 15);
  u16x8 v = {0, 0, 0, 0, 0, 0, 0, 0};
  if (rowInSec < 49) {
    const u16* src = w1p + (size_t)(s * 392 + h * 49 + rowInSec) * 416
                   + ks * 32 + ((l >> 4) & 3) * 8;
    v = *(const u16x8*)src;
  }
  *(u16x8*)(w1f + i * 8) = v;
}

// ---------------------------------------------------------------------------
// transpose chunk of x [16][392][4096] -> xt [S*4096][416] bf16 (pad cols zeroed)
__global__ __launch_bounds__(256) void k_transpose(const void* __restrict__ xraw,
                                                   const int* __restrict__ dflag,
                                                   u16* __restrict__ xt, int jg0)
{
  __shared__ u16 ts[64][72];
  const int flag = *dflag;
  const int t = threadIdx.x;
  const int j0l = blockIdx.x * 64;
  const int j0g = jg0 + j0l;
  const int c0 = blockIdx.y * 64;
  const int c_l = t >> 2;
  const int c = c0 + c_l;
  const int bb = j0g >> 12;
  const int hw0 = j0g & 4095;

  #pragma unroll
  for (int u = 0; u < 2; ++u) {
    int jp = u * 32 + (t & 3) * 8;
    u16 vv[8] = {0, 0, 0, 0, 0, 0, 0, 0};
    if (c < 392) {
      size_t base = (((size_t)(bb * 392 + c)) << 12) + hw0 + jp;
      if (flag) {
        u16x8 v = *(const u16x8*)((const u16*)xraw + base);
        #pragma unroll
        for (int i = 0; i < 8; ++i) vv[i] = v[i];
      } else {
        const float* xf = (const float*)xraw + base;
        f32x4 a = *(const f32x4*)xf;
        f32x4 b = *(const f32x4*)(xf + 4);
        #pragma unroll
        for (int i = 0; i < 4; ++i) { vv[i] = f2bf(a[i]); vv[4 + i] = f2bf(b[i]); }
      }
    }
    #pragma unroll
    for (int i = 0; i < 8; ++i) ts[jp + i][c_l] = vv[i];
  }
  __syncthreads();
  const int j_l = t >> 2;
  #pragma unroll
  for (int u = 0; u < 2; ++u) {
    int cp = u * 32 + (t & 3) * 8;
    u16x8 w;
    #pragma unroll
    for (int i = 0; i < 8; ++i) w[i] = ts[j_l][cp + i];
    int cg = c0 + cp;
    if (cg < 416) *(u16x8*)(xt + (size_t)(j0l + j_l) * 416 + cg) = w;
  }
}

// ---------------------------------------------------------------------------
// transpose chunk-local attention output att [s][392][4096] -> aout [.][416]
__global__ __launch_bounds__(256) void k_att_tr(const u16* __restrict__ att,
                                                u16* __restrict__ aout)
{
  __shared__ u16 ts[64][72];
  const int t = threadIdx.x;
  const int j0l = blockIdx.x * 64;
  const int c0 = blockIdx.y * 64;
  const int c_l = t >> 2;
  const int c = c0 + c_l;
  const int slab = j0l >> 12;
  const int hw0 = j0l & 4095;

  #pragma unroll
  for (int u = 0; u < 2; ++u) {
    int jp = u * 32 + (t & 3) * 8;
    u16x8 v = {0, 0, 0, 0, 0, 0, 0, 0};
    if (c < 392)
      v = *(const u16x8*)(att + (size_t)slab * 1605632 + (size_t)c * 4096 + hw0 + jp);
    #pragma unroll
    for (int i = 0; i < 8; ++i) ts[jp + i][c_l] = v[i];
  }
  __syncthreads();
  const int j_l = t >> 2;
  #pragma unroll
  for (int u = 0; u < 2; ++u) {
    int cp = u * 32 + (t & 3) * 8;
    u16x8 w;
    #pragma unroll
    for (int i = 0; i < 8; ++i) w[i] = ts[j_l][cp + i];
    int cg = c0 + cp;
    if (cg < 416) *(u16x8*)(aout + (size_t)(j0l + j_l) * 416 + cg) = w;
  }
}

// ---------------------------------------------------------------------------
// per-row sum/sumsq over 416 cols (pad cols are zero). One wave per row.
__global__ __launch_bounds__(256) void k_rowstats(const u16* __restrict__ buf,
                                                  float* __restrict__ sum, float* __restrict__ sq)
{
  const int t = threadIdx.x;
  const int lane = t & 63;
  const int row = blockIdx.x * 4 + (t >> 6);
  float s = 0.f, q = 0.f;
  if (lane < 52) {
    u16x8 v = *(const u16x8*)(buf + (size_t)row * 416 + lane * 8);
    #pragma unroll
    for (int i = 0; i < 8; ++i) { float f = bf2f(v[i]); s += f; q += f * f; }
  }
  #pragma unroll
  for (int d = 1; d < 64; d <<= 1) { s += __shfl_xor(s, d); q += __shfl_xor(q, d); }
  if (lane == 0) { sum[row] = s; sq[row] = q; }
}

// ---------------------------------------------------------------------------
// qkv GEMM (LN1 folded) + elementwise attention -> NCHW att.
// FRAG-MAJOR LDS (R6-verified layout): A = 8 frags x 512, B = 12 frags x 512,
// all lane-linear -> zero bank conflicts (was 1.19e7/dispatch). Per-lane
// fragment values are identical to the row-major version; only LDS addresses
// changed, so the epilogue is untouched.
__global__ __launch_bounds__(256, 2) void k_qkv(
    const u16* __restrict__ xt, const u16* __restrict__ w1f,
    const float* __restrict__ wsum1, const float* __restrict__ cb1,
    const float* __restrict__ sum1, const float* __restrict__ sq1,
    const void* __restrict__ relb, const int* __restrict__ dflag,
    u16* __restrict__ attout)
{
  __shared__ __align__(16) u16 lsA[2 * 4096];   // 2 bufs x 8 frags x 512
  __shared__ __align__(16) u16 lsB[2 * 6144];   // 2 bufs x 12 frags x 512
  const int flag = *dflag;
  const int t = threadIdx.x;
  const int wid = t >> 6, lane = t & 63;
  const int l15 = lane & 15, quad = lane >> 4;
  const int bid = blockIdx.x;
  const int h = (bid >> 3) & 7;
  const int jl0 = ((bid & 7) + ((bid >> 6) << 3)) * 128;

  // A staging: frag f = t>>6 (+4), lane l: row jl0 + f*16 + (l&15), col ((l>>4)&3)*8
  const u16* gA0 = xt + (size_t)(jl0 + (t >> 6) * 16 + (t & 15)) * 416 + ((t >> 4) & 3) * 8;
  const u16* gA1 = xt + (size_t)(jl0 + (4 + (t >> 6)) * 16 + (t & 15)) * 416 + ((t >> 4) & 3) * 8;
  // B staging: fully linear from pre-repacked w1f
  const u16* gB0 = w1f + ((size_t)(h * 12 + (t >> 6)) * 13) * 512 + (t & 63) * 8;
  const u16* gB1 = w1f + ((size_t)(h * 12 + 4 + (t >> 6)) * 13) * 512 + (t & 63) * 8;
  const u16* gB2 = w1f + ((size_t)(h * 12 + 8 + (t >> 6)) * 13) * 512 + (t & 63) * 8;

  f32x4 zero4 = {0.f, 0.f, 0.f, 0.f};
  f32x4 accq[2][4], acck[2][4], accv[2][4];
  #pragma unroll
  for (int a = 0; a < 2; ++a)
    #pragma unroll
    for (int b2 = 0; b2 < 4; ++b2) { accq[a][b2] = zero4; acck[a][b2] = zero4; accv[a][b2] = zero4; }

  auto stage = [&](int b, int ks) {
    gload16(gA0 + ks * 32, lsA + b * 4096 + t * 8);
    gload16(gA1 + ks * 32, lsA + b * 4096 + 2048 + t * 8);
    gload16(gB0 + (size_t)ks * 512, lsB + b * 6144 + t * 8);
    gload16(gB1 + (size_t)ks * 512, lsB + b * 6144 + 2048 + t * 8);
    gload16(gB2 + (size_t)ks * 512, lsB + b * 6144 + 4096 + t * 8);
  };

  stage(0, 0);
  int cur = 0;
  for (int it = 0; it < 13; ++it) {
    if (it < 12) { stage(cur ^ 1, it + 1); WAIT_VM(5); }
    else WAIT_VM(0);
    SBAR();
    SCHED_FENCE();
    const u16* A = lsA + cur * 4096;
    const u16* B = lsB + cur * 6144;
    short8 af0 = *(const short8*)(A + (2 * wid) * 512 + lane * 8);
    short8 af1 = *(const short8*)(A + (2 * wid + 1) * 512 + lane * 8);
    #pragma unroll
    for (int of = 0; of < 4; ++of) {
      short8 bq = *(const short8*)(B + of * 512 + lane * 8);
      short8 bk = *(const short8*)(B + (4 + of) * 512 + lane * 8);
      short8 bv = *(const short8*)(B + (8 + of) * 512 + lane * 8);
      accq[0][of] = mfma16(af0, bq, accq[0][of]);
      accq[1][of] = mfma16(af1, bq, accq[1][of]);
      acck[0][of] = mfma16(af0, bk, acck[0][of]);
      acck[1][of] = mfma16(af1, bk, acck[1][of]);
      accv[0][of] = mfma16(af0, bv, accv[0][of]);
      accv[1][of] = mfma16(af1, bv, accv[1][of]);
    }
    SCHED_FENCE();
    SBAR();
    cur ^= 1;
  }

  const float scale = 1.f / 7.f;
  float cq[4], wq[4], ck[4], wk[4], cv[4], wv_[4], bo[4];
  int dl[4];
  #pragma unroll
  for (int of = 0; of < 4; ++of) {
    int d = of * 16 + l15; dl[of] = d;
    int rq = h * 49 + d, rk = 392 + h * 49 + d, rv = 784 + h * 49 + d;
    wq[of] = wsum1[rq]; cq[of] = cb1[rq];
    wk[of] = wsum1[rk]; ck[of] = cb1[rk];
    wv_[of] = wsum1[rv]; cv[of] = cb1[rv];
    bo[of] = (d < 49) ? loadx(relb, h * 49 + d, flag) : 0.f;
  }
  #pragma unroll
  for (int jf = 0; jf < 2; ++jf) {
    #pragma unroll
    for (int r = 0; r < 4; ++r) {
      int jl = jl0 + wid * 32 + jf * 16 + quad * 4 + r;
      float mu = sum1[jl] * (1.f / 392.f);
      float var = sq1[jl] * (1.f / 392.f) - mu * mu;
      float rs = rsqrtf(fmaxf(var, 0.f) + 1e-5f);
      float sv[4], vv[4];
      float mx = -1e30f;
      #pragma unroll
      for (int of = 0; of < 4; ++of) {
        float qv = rs * accq[jf][of][r] + cq[of] - mu * rs * wq[of];
        float kv = rs * acck[jf][of][r] + ck[of] - mu * rs * wk[of];
        float s = (dl[of] < 49) ? (qv * scale * kv + bo[of]) : -1e30f;
        sv[of] = s; mx = fmaxf(mx, s);
        vv[of] = rs * accv[jf][of][r] + cv[of] - mu * rs * wv_[of];
      }
      #pragma unroll
      for (int d2 = 1; d2 < 16; d2 <<= 1) mx = fmaxf(mx, __shfl_xor(mx, d2));
      float sum = 0.f;
      #pragma unroll
      for (int of = 0; of < 4; ++of) { float e = __expf(sv[of] - mx); sv[of] = e; sum += e; }
      #pragma unroll
      for (int d2 = 1; d2 < 16; d2 <<= 1) sum += __shfl_xor(sum, d2);
      float inv = 1.f / sum;
      int pos = jl & 4095, slab = jl >> 12;
      size_t base = (size_t)slab * 1605632 + (size_t)h * 200704 + (size_t)pos * 49;
      #pragma unroll
      for (int of = 0; of < 4; ++of) {
        if (dl[of] < 49) attout[base + dl[of]] = f2bf(sv[of] * inv * vv[of]);
      }
    }
  }
}

// ===========================================================================
// Frag-major GEMM core (256 threads, BM=128, BN=128, BK=32) - unchanged R7.
// ===========================================================================

// proj GEMM + bias + residual(xt) -> x2t
__global__ __launch_bounds__(256, 4) void k_proj(
    const u16* __restrict__ aout, const u16* __restrict__ wppf,
    const void* __restrict__ projb, const int* __restrict__ dflag,
    const u16* __restrict__ xt, u16* __restrict__ x2t)
{
  __shared__ __align__(16) u16 lsA[2 * 4096];
  __shared__ __align__(16) u16 lsB[2 * 4096];
  const int flag = *dflag;
  const int t = threadIdx.x;
  const int w = t >> 6, lane = t & 63;
  const int l15 = lane & 15, quad = (lane >> 4) & 3;
  const int jl0 = blockIdx.x * 128;
  const int y = blockIdx.y, o0 = y * 128;
  const int NK = 13;
  const int wm = w >> 1, wn = w & 1;

  const u16* gA0 = aout + (size_t)(jl0 + w * 16 + l15) * 416 + quad * 8;
  const u16* gA1 = aout + (size_t)(jl0 + (4 + w) * 16 + l15) * 416 + quad * 8;
  const u16* gB0 = wppf + ((size_t)(y * 8 + w) * NK) * 512 + lane * 8;
  const u16* gB1 = wppf + ((size_t)(y * 8 + 4 + w) * NK) * 512 + lane * 8;

  f32x4 zero4 = {0.f, 0.f, 0.f, 0.f};
  f32x4 acc[4][4];
  #pragma unroll
  for (int m = 0; m < 4; ++m)
    #pragma unroll
    for (int n = 0; n < 4; ++n) acc[m][n] = zero4;

  auto stage = [&](int b, int ks) {
    gload16(gA0 + ks * 32, lsA + b * 4096 + w * 512 + lane * 8);
    gload16(gA1 + ks * 32, lsA + b * 4096 + (4 + w) * 512 + lane * 8);
    gload16(gB0 + (size_t)ks * 512, lsB + b * 4096 + w * 512 + lane * 8);
    gload16(gB1 + (size_t)ks * 512, lsB + b * 4096 + (4 + w) * 512 + lane * 8);
  };

  stage(0, 0);
  int cur = 0;
  for (int ks = 0; ks < NK; ++ks) {
    if (ks + 1 < NK) { stage(cur ^ 1, ks + 1); WAIT_VM(4); }
    else WAIT_VM(0);
    SBAR();
    SCHED_FENCE();
    const u16* A = lsA + cur * 4096;
    const u16* B = lsB + cur * 4096;
    short8 af[4];
    #pragma unroll
    for (int m = 0; m < 4; ++m)
      af[m] = *(const short8*)(A + (wm * 4 + m) * 512 + lane * 8);
    #pragma unroll
    for (int n = 0; n < 4; ++n) {
      short8 bf = *(const short8*)(B + (wn * 4 + n) * 512 + lane * 8);
      #pragma unroll
      for (int m = 0; m < 4; ++m) acc[m][n] = mfma16(af[m], bf, acc[m][n]);
    }
    SCHED_FENCE();
    SBAR();
    cur ^= 1;
  }

  float pb[4]; int og[4];
  #pragma unroll
  for (int n = 0; n < 4; ++n) {
    int o = o0 + wn * 64 + n * 16 + l15; og[n] = o;
    pb[n] = (o < 392) ? loadx(projb, o, flag) : 0.f;
  }
  const int row0 = jl0 + wm * 64;
  #pragma unroll
  for (int m = 0; m < 4; ++m) {
    #pragma unroll
    for (int r = 0; r < 4; ++r) {
      int jl = row0 + m * 16 + quad * 4 + r;
      #pragma unroll
      for (int n = 0; n < 4; ++n) {
        int o = og[n];
        if (o < 392) {
          float val = acc[m][n][r] + pb[n] + bf2f(xt[(size_t)jl * 416 + o]);
          x2t[(size_t)jl * 416 + o] = f2bf(val);
        } else if (o < 416) {
          x2t[(size_t)jl * 416 + o] = 0;
        }
      }
    }
  }
}

// fc1 GEMM (LN2 folded) + exact gelu -> ut
__global__ __launch_bounds__(256, 4) void k_fc1(
    const u16* __restrict__ x2t, const u16* __restrict__ w3pf,
    const float* __restrict__ wsum3, const float* __restrict__ cb3,
    const float* __restrict__ sum2, const float* __restrict__ sq2,
    u16* __restrict__ ut)
{
  __shared__ __align__(16) u16 lsA[2 * 4096];
  __shared__ __align__(16) u16 lsB[2 * 4096];
  const int t = threadIdx.x;
  const int w = t >> 6, lane = t & 63;
  const int l15 = lane & 15, quad = (lane >> 4) & 3;
  const int jl0 = blockIdx.x * 128;
  const int y = blockIdx.y, o0 = y * 128;
  const int NK = 13;
  const int wm = w >> 1, wn = w & 1;

  const u16* gA0 = x2t + (size_t)(jl0 + w * 16 + l15) * 416 + quad * 8;
  const u16* gA1 = x2t + (size_t)(jl0 + (4 + w) * 16 + l15) * 416 + quad * 8;
  const u16* gB0 = w3pf + ((size_t)(y * 8 + w) * NK) * 512 + lane * 8;
  const u16* gB1 = w3pf + ((size_t)(y * 8 + 4 + w) * NK) * 512 + lane * 8;

  f32x4 zero4 = {0.f, 0.f, 0.f, 0.f};
  f32x4 acc[4][4];
  #pragma unroll
  for (int m = 0; m < 4; ++m)
    #pragma unroll
    for (int n = 0; n < 4; ++n) acc[m][n] = zero4;

  auto stage = [&](int b, int ks) {
    gload16(gA0 + ks * 32, lsA + b * 4096 + w * 512 + lane * 8);
    gload16(gA1 + ks * 32, lsA + b * 4096 + (4 + w) * 512 + lane * 8);
    gload16(gB0 + (size_t)ks * 512, lsB + b * 4096 + w * 512 + lane * 8);
    gload16(gB1 + (size_t)ks * 512, lsB + b * 4096 + (4 + w) * 512 + lane * 8);
  };

  stage(0, 0);
  int cur = 0;
  for (int ks = 0; ks < NK; ++ks) {
    if (ks + 1 < NK) { stage(cur ^ 1, ks + 1); WAIT_VM(4); }
    else WAIT_VM(0);
    SBAR();
    SCHED_FENCE();
    const u16* A = lsA + cur * 4096;
    const u16* B = lsB + cur * 4096;
    short8 af[4];
    #pragma unroll
    for (int m = 0; m < 4; ++m)
      af[m] = *(const short8*)(A + (wm * 4 + m) * 512 + lane * 8);
    #pragma unroll
    for (int n = 0; n < 4; ++n) {
      short8 bf = *(const short8*)(B + (wn * 4 + n) * 512 + lane * 8);
      #pragma unroll
      for (int m = 0; m < 4; ++m) acc[m][n] = mfma16(af[m], bf, acc[m][n]);
    }
    SCHED_FENCE();
    SBAR();
    cur ^= 1;
  }

  float c3[4], w3[4]; int og[4];
  #pragma unroll
  for (int n = 0; n < 4; ++n) {
    int o = o0 + wn * 64 + n * 16 + l15; og[n] = o;
    c3[n] = cb3[o]; w3[n] = wsum3[o];
  }
  const int row0 = jl0 + wm * 64;
  #pragma unroll
  for (int m = 0; m < 4; ++m) {
    #pragma unroll
    for (int r = 0; r < 4; ++r) {
      int jl = row0 + m * 16 + quad * 4 + r;
      float mu = sum2[jl] * (1.f / 392.f);
      float var = sq2[jl] * (1.f / 392.f) - mu * mu;
      float rs = rsqrtf(fmaxf(var, 0.f) + 1e-5f);
      #pragma unroll
      for (int n = 0; n < 4; ++n) {
        if (og[n] < 1568) {
          float u = rs * acc[m][n][r] + c3[n] - mu * rs * w3[n];
          float gl = 0.5f * u * (1.f + erff(u * 0.70710678118654752f));
          ut[(size_t)jl * 1568 + og[n]] = f2bf(gl);
        }
      }
    }
  }
}

// fc2 GEMM + bias + residual(x2) -> final output in NCHW
__global__ __launch_bounds__(256, 4) void k_fc2(
    const u16* __restrict__ ut, const u16* __restrict__ wfpf,
    const void* __restrict__ fc2b, const int* __restrict__ dflag,
    const u16* __restrict__ x2t, void* __restrict__ outp, int jfg0)
{
  __shared__ __align__(16) u16 lsA[2 * 4096];
  __shared__ __align__(16) u16 lsB[2 * 4096];
  const int flag = *dflag;
  const int t = threadIdx.x;
  const int w = t >> 6, lane = t & 63;
  const int l15 = lane & 15, quad = (lane >> 4) & 3;
  const int jl0 = blockIdx.x * 128;
  const int y = blockIdx.y, o0 = y * 128;
  const int NK = 49;
  const int wm = w >> 1, wn = w & 1;

  const u16* gA0 = ut + (size_t)(jl0 + w * 16 + l15) * 1568 + quad * 8;
  const u16* gA1 = ut + (size_t)(jl0 + (4 + w) * 16 + l15) * 1568 + quad * 8;
  const u16* gB0 = wfpf + ((size_t)(y * 8 + w) * NK) * 512 + lane * 8;
  const u16* gB1 = wfpf + ((size_t)(y * 8 + 4 + w) * NK) * 512 + lane * 8;

  f32x4 zero4 = {0.f, 0.f, 0.f, 0.f};
  f32x4 acc[4][4];
  #pragma unroll
  for (int m = 0; m < 4; ++m)
    #pragma unroll
    for (int n = 0; n < 4; ++n) acc[m][n] = zero4;

  auto stage = [&](int b, int ks) {
    gload16(gA0 + ks * 32, lsA + b * 4096 + w * 512 + lane * 8);
    gload16(gA1 + ks * 32, lsA + b * 4096 + (4 + w) * 512 + lane * 8);
    gload16(gB0 + (size_t)ks * 512, lsB + b * 4096 + w * 512 + lane * 8);
    gload16(gB1 + (size_t)ks * 512, lsB + b * 4096 + (4 + w) * 512 + lane * 8);
  };

  stage(0, 0);
  int cur = 0;
  for (int ks = 0; ks < NK; ++ks) {
    if (ks + 1 < NK) { stage(cur ^ 1, ks + 1); WAIT_VM(4); }
    else WAIT_VM(0);
    SBAR();
    SCHED_FENCE();
    const u16* A = lsA + cur * 4096;
    const u16* B = lsB + cur * 4096;
    short8 af[4];
    #pragma unroll
    for (int m = 0; m < 4; ++m)
      af[m] = *(const short8*)(A + (wm * 4 + m) * 512 + lane * 8);
    #pragma unroll
    for (int n = 0; n < 4; ++n) {
      short8 bf = *(const short8*)(B + (wn * 4 + n) * 512 + lane * 8);
      #pragma unroll
      for (int m = 0; m < 4; ++m) acc[m][n] = mfma16(af[m], bf, acc[m][n]);
    }
    SCHED_FENCE();
    SBAR();
    cur ^= 1;
  }

  float fb4[4]; int og[4];
  #pragma unroll
  for (int n = 0; n < 4; ++n) {
    int o = o0 + wn * 64 + n * 16 + l15; og[n] = o;
    fb4[n] = (o < 392) ? loadx(fc2b, o, flag) : 0.f;
  }
  const int row0 = jl0 + wm * 64;
  #pragma unroll
  for (int m = 0; m < 4; ++m) {
    int jlbase = row0 + m * 16 + quad * 4;
    int jgbase = jfg0 + jlbase;
    int bslab = jgbase >> 12;
    int hw = jgbase & 4095;
    #pragma unroll
    for (int n = 0; n < 4; ++n) {
      if (og[n] < 392) {
        float v4[4];
        #pragma unroll
        for (int r = 0; r < 4; ++r)
          v4[r] = acc[m][n][r] + fb4[n] + bf2f(x2t[(size_t)(jlbase + r) * 416 + og[n]]);
        size_t obase = (((size_t)(bslab * 392 + og[n])) << 12) + hw;
        if (flag) {
          u16x4 pk;
          #pragma unroll
          for (int r = 0; r < 4; ++r) pk[r] = f2bf(v4[r]);
          *(u16x4*)((u16*)outp + obase) = pk;
        } else {
          f32x4 pk;
          #pragma unroll
          for (int r = 0; r < 4; ++r) pk[r] = v4[r];
          *(f32x4*)((float*)outp + obase) = pk;
        }
      }
    }
  }
}

// ---------------------------------------------------------------------------
extern "C" void kernel_launch(void* const* d_in, const int* in_sizes, int n_in,
                              void* d_out, int out_size, void* d_ws, size_t ws_size,
                              hipStream_t stream)
{
  if (n_in != 14 || in_sizes[0] != 16 * 392 * 64 * 64 || out_size != 16 * 392 * 64 * 64 ||
      in_sizes[3] != 3 * 392 * 392 || in_sizes[5] != 8 * 7 * 7 ||
      in_sizes[10] != 1568 * 392 || in_sizes[12] != 392 * 1568) {
    return;
  }

  const void* x     = d_in[0];
  const void* g1    = d_in[1];
  const void* b1    = d_in[2];
  const void* qkvw  = d_in[3];
  const void* qkvb  = d_in[4];
  const void* relb  = d_in[5];
  const void* projw = d_in[6];
  const void* projb = d_in[7];
  const void* g2    = d_in[8];
  const void* b2    = d_in[9];
  const void* fc1w  = d_in[10];
  const void* fc1b  = d_in[11];
  const void* fc2w  = d_in[12];
  const void* fc2b  = d_in[13];

  int S = 0, F = 0;
  {
    const int cand[8][2] = {{16,8},{16,4},{8,4},{8,2},{4,2},{4,1},{2,1},{1,1}};
    for (int i = 0; i < 8; ++i) {
      size_t nb = (size_t)cand[i][0] * 4096 * 416 * 2 * 3
                + (size_t)cand[i][1] * 4096 * 1568 * 2
                + (size_t)24 * 1024 * 1024;                 // weights + stats + slack
      if (nb <= ws_size) { S = cand[i][0]; F = cand[i][1]; break; }
    }
    if (S == 0) return;
  }

  char* wsb = (char*)d_ws;
  size_t off = 0;
  auto alloc = [&](size_t bytes) -> void* {
    void* p = wsb + off;
    off = (off + bytes + 255) & ~(size_t)255;
    return p;
  };
  int*  dflag = (int*)alloc(256);
  u16* xt    = (u16*)alloc((size_t)S * 4096 * 416 * 2);
  u16* aout  = (u16*)alloc((size_t)S * 4096 * 416 * 2);
  u16* x2t   = (u16*)alloc((size_t)S * 4096 * 416 * 2);
  u16* ut    = (u16*)alloc((size_t)F * 4096 * 1568 * 2);
  u16* w1p   = (u16*)alloc((size_t)1200 * 416 * 2);
  u16* w1f   = (u16*)alloc((size_t)8 * 12 * 13 * 512 * 2); // qkv frag-major
  u16* w3r   = (u16*)alloc((size_t)2048 * 416 * 2);    // fc1 folded, row-major tmp
  u16* w3pf  = (u16*)alloc((size_t)2048 * 416 * 2);    // fc1 frag-major
  u16* wpr   = (u16*)alloc((size_t)512 * 416 * 2);     // proj row-major tmp
  u16* wppf  = (u16*)alloc((size_t)512 * 416 * 2);     // proj frag-major
  u16* wfr   = (u16*)alloc((size_t)512 * 1568 * 2);    // fc2 row-major tmp
  u16* wfpf  = (u16*)alloc((size_t)512 * 1568 * 2);    // fc2 frag-major
  float* wsum1 = (float*)alloc(1200 * 4);
  float* cb1   = (float*)alloc(1200 * 4);
  float* wsum3 = (float*)alloc(2048 * 4);
  float* cb3   = (float*)alloc(2048 * 4);
  float* sum1  = (float*)alloc((size_t)65536 * 4);
  float* sq1   = (float*)alloc((size_t)65536 * 4);
  float* sum2  = (float*)alloc((size_t)65536 * 4);
  float* sq2   = (float*)alloc((size_t)65536 * 4);

  u16* att = x2t;   // aliasing unchanged (dead before k_proj writes x2t)

  k_detect<<<1, 256, 0, stream>>>((const unsigned int*)x, dflag);

  k_prep_fold<<<1200, 64, 0, stream>>>(qkvw, g1, b1, qkvb, dflag, w1p, wsum1, cb1, 1176, 392, 416);
  k_prep_fold<<<2048, 64, 0, stream>>>(fc1w, g2, b2, fc1b, dflag, w3r, wsum3, cb3, 1568, 392, 416);
  k_prep_pad<<<(512 * 416 + 255) / 256, 256, 0, stream>>>(projw, dflag, wpr, 392, 392, 416, (long)512 * 416);
  k_prep_pad<<<(512 * 1568 + 255) / 256, 256, 0, stream>>>(fc2w, dflag, wfr, 392, 1568, 1568, (long)512 * 1568);
  k_repack_qkv<<<(79872 + 255) / 256, 256, 0, stream>>>(w1p, w1f);
  k_repack<<<((2048 * 416 / 8) + 255) / 256, 256, 0, stream>>>(w3r, w3pf, 2048, 416);
  k_repack<<<((512 * 416 / 8) + 255) / 256, 256, 0, stream>>>(wpr, wppf, 512, 416);
  k_repack<<<((512 * 1568 / 8) + 255) / 256, 256, 0, stream>>>(wfr, wfpf, 512, 1568);

  for (int c0 = 0; c0 < 16; c0 += S) {
    const int jg0 = c0 * 4096;
    k_transpose<<<dim3(S * 64, 7), 256, 0, stream>>>(x, dflag, xt, jg0);
    k_rowstats<<<S * 1024, 256, 0, stream>>>(xt, sum1, sq1);
    k_qkv<<<dim3(S * 256), 256, 0, stream>>>(xt, w1f, wsum1, cb1, sum1, sq1, relb, dflag, att);
    k_att_tr<<<dim3(S * 64, 7), 256, 0, stream>>>(att, aout);
    k_proj<<<dim3(S * 32, 4), 256, 0, stream>>>(aout, wppf, projb, dflag, xt, x2t);
    k_rowstats<<<S * 1024, 256, 0, stream>>>(x2t, sum2, sq2);
    for (int f0 = 0; f0 < S; f0 += F) {
      const int jfg0 = (c0 + f0) * 4096;
      const u16* x2sub = x2t + (size_t)f0 * 4096 * 416;
      k_fc1<<<dim3(F * 32, 13), 256, 0, stream>>>(x2sub, w3pf, wsum3, cb3,
                                                  sum2 + (size_t)f0 * 4096, sq2 + (size_t)f0 * 4096, ut);
      k_fc2<<<dim3(F * 32, 4), 256, 0, stream>>>(ut, wfpf, fc2b, dflag, x2sub, d_out, jfg0);
    }
  }
}